// Round 1
// 1582.770 us; speedup vs baseline: 1.0538x; 1.0538x over previous
//
#include <hip/hip_runtime.h>

// DUST_65085934403760 : LIHT sparse-coding + window attention, MI355X.
// Round 8: replace the three fp32 VALU GEMMs (3x266us, MfmaUtil=0) with a
// bf16x6 split-precision MFMA GEMM (fp32-grade accuracy on the matrix cores).
//  - Each fp32 operand is pre-split into 3 bf16 planes (h1+h2+h3, residuals
//    exact by Sterbenz); GEMM accumulates the 6 significant cross-products
//    (1,1),(1,2),(2,1),(2,2),(1,3),(3,1) in fp32 MFMA accumulators. Dropped
//    terms <= 2^-24 relative -> same error class as fp32.
//  - gemm_bf6: 128x64 tile, 4 waves, K-chunk 32, mfma_f32_16x16x32_bf16,
//    width-16 global_load_lds staging, K-grouped LDS layout ([g][row]*16B)
//    for bank-uniform ds_read_b128 frag loads, double-buffered 2-phase loop,
//    XCD-chunked block swizzle (512%8==0 -> bijective; 3MB A-panel per XCD L2).
//  - GEMM1 B-operand = Wd as-is (x @ Wd^T), GEMM3 B-operand = S (symmetric),
//    GEMM2 needs Wd^T -> transposing split kernel tconv3.
//  - All non-GEMM kernels (topk, spapply_sl, attention, norm) are the proven
//    round-3/7 versions, verbatim.

#define DD 2048
#define NB 2048

using short8v  = __attribute__((ext_vector_type(8))) short;
using ushort8v = __attribute__((ext_vector_type(8))) unsigned short;
using ushort4v = __attribute__((ext_vector_type(4))) unsigned short;
using float4v  = __attribute__((ext_vector_type(4))) float;

// ---------------------------------------------------------------- helpers
__device__ __forceinline__ unsigned short f2bf(float f) {
  // round-to-nearest-even fp32 -> bf16 (inputs are finite, moderate range)
  unsigned u = __float_as_uint(f);
  u = u + 0x7fffu + ((u >> 16) & 1u);
  return (unsigned short)(u >> 16);
}
__device__ __forceinline__ float bf2f(unsigned short h) {
  return __uint_as_float((unsigned)h << 16);
}
__device__ __forceinline__ void gload16(const void* g, void* l) {
  __builtin_amdgcn_global_load_lds((const __attribute__((address_space(1))) void*)g,
                                   (__attribute__((address_space(3))) void*)l,
                                   16, 0, 0);
}

// --------------------------------------------------- fp32 -> 3 bf16 planes
// out[p][i] : h1,h2,h3 with v = h1 + h2 + h3 + O(2^-27 v)
__global__ __launch_bounds__(256)
void conv3(const float* __restrict__ in, unsigned short* __restrict__ p0,
           unsigned short* __restrict__ p1, unsigned short* __restrict__ p2) {
  const size_t i0 = ((size_t)blockIdx.x * 256 + threadIdx.x) * 8;
  float4 a = *(const float4*)(in + i0);
  float4 b = *(const float4*)(in + i0 + 4);
  float v[8] = {a.x, a.y, a.z, a.w, b.x, b.y, b.z, b.w};
  ushort8v o0, o1, o2;
#pragma unroll
  for (int e = 0; e < 8; ++e) {
    unsigned short h0 = f2bf(v[e]);  float r1 = v[e] - bf2f(h0);
    unsigned short h1 = f2bf(r1);    float r2 = r1 - bf2f(h1);
    unsigned short h2 = f2bf(r2);
    o0[e] = h0; o1[e] = h1; o2[e] = h2;
  }
  *(ushort8v*)(p0 + i0) = o0;
  *(ushort8v*)(p1 + i0) = o1;
  *(ushort8v*)(p2 + i0) = o2;
}

// ------------------------------------- transposing split: planes of in^T
// in: [K][N] fp32 row-major; planes: [N][K] bf16 (K contiguous).
__global__ __launch_bounds__(256)
void tconv3(const float* __restrict__ in, unsigned short* __restrict__ p0,
            unsigned short* __restrict__ p1, unsigned short* __restrict__ p2) {
  __shared__ unsigned short t0[32][36], t1[32][36], t2[32][36];
  const int n0 = blockIdx.x * 32, k0 = blockIdx.y * 32;
  const int rw = threadIdx.x >> 3, c4 = (threadIdx.x & 7) * 4;
  float4 v = *(const float4*)(in + (size_t)(k0 + rw) * DD + n0 + c4);
  float vv[4] = {v.x, v.y, v.z, v.w};
#pragma unroll
  for (int e = 0; e < 4; ++e) {
    unsigned short a0 = f2bf(vv[e]); float r1 = vv[e] - bf2f(a0);
    unsigned short a1 = f2bf(r1);    float r2 = r1 - bf2f(a1);
    unsigned short a2 = f2bf(r2);
    t0[rw][c4 + e] = a0; t1[rw][c4 + e] = a1; t2[rw][c4 + e] = a2;
  }
  __syncthreads();
  const size_t o = (size_t)(n0 + rw) * DD + k0 + c4;
  ushort4v w0, w1, w2;
#pragma unroll
  for (int e = 0; e < 4; ++e) {
    w0[e] = t0[c4 + e][rw]; w1[e] = t1[c4 + e][rw]; w2[e] = t2[c4 + e][rw];
  }
  *(ushort4v*)(p0 + o) = w0;
  *(ushort4v*)(p1 + o) = w1;
  *(ushort4v*)(p2 + o) = w2;
}

// --------------------------------------------------- bf16x6 MFMA GEMM
// C[m,n] = sum_k A[m,k]*B'[n,k]  (+ Cadd[m,n]), A/B' given as 3 bf16 planes
// each [2048][2048] K-contiguous. Tile 128(m) x 64(n), K-chunk 32, 4 waves.
// LDS per buffer: A 3*[4 g][128 row]*16B = 24KB, B 3*[4 g][64 col]*16B = 12KB.
#define LDS_B_OFF 24576
#define LDS_BUF   36864

template<int ADD>
__global__ __launch_bounds__(256, 2)
void gemm_bf6(const unsigned short* __restrict__ PA,
              const unsigned short* __restrict__ PB,
              const float* __restrict__ Cadd, float* __restrict__ Cout) {
  __shared__ char lds[2 * LDS_BUF];
  const int tid = threadIdx.x, lane = tid & 63, wid = tid >> 6;

  // XCD-chunked swizzle: round-robin dispatch -> XCD x gets 64 consecutive
  // tiles = 2 full m-rows; its A-panel slice (256 rows * 3 planes = 3MB)
  // stays resident in the XCD's 4MB L2.
  int lin = (int)blockIdx.x;
  lin = (lin & 7) * 64 + (lin >> 3);            // bijective (512 % 8 == 0)
  const int m0 = (lin >> 5) * 128;
  const int n0 = (lin & 31) * 64;

  const int aq = wid * 6;   // 6 A-staging instrs per wave (24 total)
  const int bq = wid * 3;   // 3 B-staging instrs per wave (12 total)

  auto stage = [&](char* base, int kc) {
#pragma unroll
    for (int i = 0; i < 6; ++i) {               // A planes
      const int t = aq + i, p = t >> 3, q = t & 7;
      const int row = (q & 1) * 64 + lane, g = q >> 1;
      gload16(PA + ((size_t)p << 22) + (size_t)(m0 + row) * DD + (kc + g * 8),
              base + p * 8192 + q * 1024);
    }
#pragma unroll
    for (int i = 0; i < 3; ++i) {               // B planes
      const int t = bq + i, p = t >> 2, q = t & 3;
      gload16(PB + ((size_t)p << 22) + (size_t)(n0 + lane) * DD + (kc + q * 8),
              base + LDS_B_OFF + p * 4096 + q * 1024);
    }
  };

  float4v acc[4][2] = {};

  // wave -> 64x32 output sub-tile; frag addressing (K-grouped LDS layout):
  // A unit = g*128 + row, B unit = g*64 + col; lanes 0..15 hit consecutive
  // units -> bank-uniform ds_read_b128.
  const int rsel = (wid >> 1) * 64;
  const int csel = (wid & 1) * 32;
  const int g16  = lane >> 4;
  const int l15  = lane & 15;
  const int aoff = g16 * 2048 + (rsel + l15) * 16;              // + p*8192 + mg*256
  const int boff = LDS_B_OFF + g16 * 1024 + (csel + l15) * 16;  // + p*4096 + ng*256

  stage(lds, 0);
  __syncthreads();

  for (int c = 0; c < 64; ++c) {
    char* cur = lds + (c & 1) * LDS_BUF;
    if (c < 63) stage(lds + ((c & 1) ^ 1) * LDS_BUF, (c + 1) * 32);

    short8v b0[2], b1[2], b2[2];
#pragma unroll
    for (int ng = 0; ng < 2; ++ng) {
      b0[ng] = *(const short8v*)(cur + boff + 0 * 4096 + ng * 256);
      b1[ng] = *(const short8v*)(cur + boff + 1 * 4096 + ng * 256);
      b2[ng] = *(const short8v*)(cur + boff + 2 * 4096 + ng * 256);
    }
#pragma unroll
    for (int mg = 0; mg < 4; ++mg) {
      const short8v a0 = *(const short8v*)(cur + 0 * 8192 + aoff + mg * 256);
      const short8v a1 = *(const short8v*)(cur + 1 * 8192 + aoff + mg * 256);
      const short8v a2 = *(const short8v*)(cur + 2 * 8192 + aoff + mg * 256);
#pragma unroll
      for (int ng = 0; ng < 2; ++ng) {
        float4v t = acc[mg][ng];
        t = __builtin_amdgcn_mfma_f32_16x16x32_bf16(a0, b0[ng], t, 0, 0, 0); // h1*h1
        t = __builtin_amdgcn_mfma_f32_16x16x32_bf16(a0, b1[ng], t, 0, 0, 0); // h1*h2
        t = __builtin_amdgcn_mfma_f32_16x16x32_bf16(a1, b0[ng], t, 0, 0, 0); // h2*h1
        t = __builtin_amdgcn_mfma_f32_16x16x32_bf16(a1, b1[ng], t, 0, 0, 0); // h2*h2
        t = __builtin_amdgcn_mfma_f32_16x16x32_bf16(a0, b2[ng], t, 0, 0, 0); // h1*h3
        t = __builtin_amdgcn_mfma_f32_16x16x32_bf16(a2, b0[ng], t, 0, 0, 0); // h3*h1
        acc[mg][ng] = t;
      }
    }
    __syncthreads();   // drains vmcnt (next buffer ready) + read-done fence
  }

  // C/D layout (m89-verified): col = lane&15, row = (lane>>4)*4 + reg.
  const int row0 = m0 + rsel + g16 * 4;
  const int col0 = n0 + csel + l15;
#pragma unroll
  for (int mg = 0; mg < 4; ++mg)
#pragma unroll
    for (int ng = 0; ng < 2; ++ng)
#pragma unroll
      for (int r = 0; r < 4; ++r) {
        const size_t o = (size_t)(row0 + mg * 16 + r) * DD + col0 + ng * 16;
        float v = acc[mg][ng][r];
        if (ADD) v += Cadd[o];
        Cout[o] = v;
      }
}

// ------------------------------------ XCD-sliced sparse apply (1 wave/block)
template<int HASBASE>
__global__ __launch_bounds__(64)
void spapply_sl(const float* __restrict__ M, const float* __restrict__ baseB,
                float* __restrict__ outF, const unsigned* __restrict__ sidx,
                const float* __restrict__ sval, const int* __restrict__ scnt) {
  const int b = blockIdx.y, lane = threadIdx.x;
  const int col = blockIdx.x * 256 + lane * 4;
  const int nc = scnt[b];
  const unsigned* ip = sidx + b * 64;
  const float* vp = sval + b * 64;
  const size_t ro = (size_t)b * DD + col;
  float4 a;
  if (HASBASE) a = *(const float4*)&baseB[ro];
  else         a = make_float4(0.f, 0.f, 0.f, 0.f);
  for (int t = 0; t < nc; ++t) {
    const unsigned j = ip[t];
    const float v = vp[t];
    float4 m = *(const float4*)&M[(size_t)j * DD + col];
    a.x = fmaf(v, m.x, a.x); a.y = fmaf(v, m.y, a.y);
    a.z = fmaf(v, m.z, a.z); a.w = fmaf(v, m.w, a.w);
  }
  *(float4*)&outF[ro] = a;
}

// ------------------------------------------------------------ top-k (1 wave)
__global__ __launch_bounds__(64)
void topk_kernel(const float* __restrict__ src, unsigned* __restrict__ sidx,
                 float* __restrict__ sval, int* __restrict__ scnt,
                 float* __restrict__ dense, float* __restrict__ mD,
                 int finalMode) {
  const int b = blockIdx.x;
  const int lane = threadIdx.x;
  const float* row = src + (size_t)b * DD;
  float v[32]; unsigned ab[32];
#pragma unroll
  for (int e4 = 0; e4 < 8; ++e4) {
    float4 t = *(const float4*)&row[e4*256 + lane*4];
    v[e4*4+0]=t.x; v[e4*4+1]=t.y; v[e4*4+2]=t.z; v[e4*4+3]=t.w;
  }
#pragma unroll
  for (int e = 0; e < 32; ++e) ab[e] = __float_as_uint(v[e]) & 0x7fffffffu;

  unsigned mxb = 0;
#pragma unroll
  for (int e = 0; e < 32; ++e) mxb = ab[e] > mxb ? ab[e] : mxb;
  for (int off = 32; off; off >>= 1) {
    unsigned o = (unsigned)__shfl_down((int)mxb, off);
    mxb = o > mxb ? o : mxb;
  }
  mxb = (unsigned)__shfl((int)mxb, 0);
  const int emax = (int)(mxb >> 23);

  int eStar = 0, cntAbove = 0;
  {
    int prevc = 0;
    for (int e = emax; e >= 0; --e) {
      unsigned T = ((unsigned)e) << 23;
      int c = 0;
#pragma unroll
      for (int k = 0; k < 32; ++k) c += (ab[k] >= T) ? 1 : 0;
      for (int off = 32; off; off >>= 1) c += __shfl_down(c, off);
      c = __shfl(c, 0);
      if (c >= 50) { eStar = e; cntAbove = prevc; break; }
      prevc = c;
    }
  }
  unsigned kth = ((unsigned)eStar) << 23;
  int kneed = 50 - cntAbove;

  __shared__ int hist[256];
  __shared__ int sh_sel, sh_kneed;
  for (int p = 0; p < 3; ++p) {
    const unsigned mask = (p==0) ? 0x7F800000u : (p==1) ? 0x7FFF8000u : 0x7FFFFF80u;
    const int sh = (p==0) ? 15 : (p==1) ? 7 : 0;
    for (int t = lane; t < 256; t += 64) hist[t] = 0;
    __syncthreads();
#pragma unroll
    for (int e = 0; e < 32; ++e)
      if ((ab[e] & mask) == kth) atomicAdd(&hist[(ab[e] >> sh) & 0xFF], 1);
    __syncthreads();
    int h0 = hist[lane*4+0], h1 = hist[lane*4+1], h2 = hist[lane*4+2], h3 = hist[lane*4+3];
    int s = h0 + h1 + h2 + h3;
    int x = s;
    for (int off = 1; off < 64; off <<= 1) {
      int y = __shfl_down(x, off);
      if (lane + off < 64) x += y;
    }
    int excl = x - s;
    int c3 = excl + h3, c2 = c3 + h2, c1 = c2 + h1, c0 = c1 + h0;
    if (c0 >= kneed && c1   < kneed) { sh_sel = lane*4+0; sh_kneed = kneed - c1;  }
    if (c1 >= kneed && c2   < kneed) { sh_sel = lane*4+1; sh_kneed = kneed - c2;  }
    if (c2 >= kneed && c3   < kneed) { sh_sel = lane*4+2; sh_kneed = kneed - c3;  }
    if (c3 >= kneed && excl < kneed) { sh_sel = lane*4+3; sh_kneed = kneed - excl;}
    __syncthreads();
    kth |= ((unsigned)sh_sel) << sh;
    kneed = sh_kneed;
    __syncthreads();
  }

  int base = 0;
#pragma unroll
  for (int e4 = 0; e4 < 8; ++e4) {
    float o[4];
#pragma unroll
    for (int qq = 0; qq < 4; ++qq) {
      const int e = e4*4 + qq;
      const bool sel = ab[e] >= kth;
      unsigned long long msk = __ballot(sel);
      int pre = __popcll(msk & ((1ull << lane) - 1ull));
      const unsigned gi = (unsigned)(e4*256 + lane*4 + qq);
      if (sel) {
        int slot = base + pre;
        if (slot < 64) { sidx[b*64+slot] = gi; sval[b*64+slot] = v[e]; }
        if (finalMode) atomicAdd(&mD[gi & 1023u], v[e]*v[e]);
      }
      base += __popcll(msk);
      o[qq] = sel ? v[e] : 0.f;
    }
    if (finalMode) {
      float4 t = {o[0],o[1],o[2],o[3]};
      *(float4*)&dense[(size_t)b*DD + e4*256 + lane*4] = t;
    }
  }
  if (lane == 0) scnt[b] = base < 64 ? base : 64;
}

// ------------------------------------------------------------- attention bits
__global__ __launch_bounds__(256)
void attdot_kernel(const float* __restrict__ prev, const float* __restrict__ U,
                   float* __restrict__ att) {
  const int b = blockIdx.x, p = blockIdx.y, tid = threadIdx.x;
  const float* pr = prev + ((size_t)p*NB + b) * DD;
  const float* u  = U + (size_t)b * DD;
  float s = 0.f;
#pragma unroll
  for (int h = 0; h < 2; ++h) {
    int i = (tid + h*256) * 4;
    float4 a = *(const float4*)&pr[i];
    float4 c = *(const float4*)&u[i];
    s += a.x*c.x + a.y*c.y + a.z*c.z + a.w*c.w;
  }
  for (int off = 32; off; off >>= 1) s += __shfl_down(s, off);
  __shared__ float ps[4];
  if ((tid & 63) == 0) ps[tid >> 6] = s;
  __syncthreads();
  if (tid == 0) att[(size_t)p*NB + b] = ps[0]+ps[1]+ps[2]+ps[3];
}

__global__ __launch_bounds__(256)
void softmax_kernel(const float* __restrict__ att, float* __restrict__ attw) {
  const int p = blockIdx.x, tid = threadIdx.x;
  const float* a = att + (size_t)p*NB;
  float loc[8]; float mx = -3.4e38f;
#pragma unroll
  for (int h = 0; h < 8; ++h) { loc[h] = a[tid + h*256]; mx = fmaxf(mx, loc[h]); }
  for (int off = 32; off; off >>= 1) mx = fmaxf(mx, __shfl_down(mx, off));
  __shared__ float ps[4]; __shared__ float sh_m, sh_s;
  if ((tid & 63) == 0) ps[tid >> 6] = mx;
  __syncthreads();
  if (tid == 0) sh_m = fmaxf(fmaxf(ps[0],ps[1]), fmaxf(ps[2],ps[3]));
  __syncthreads();
  const float m = sh_m;
  float sum = 0.f;
#pragma unroll
  for (int h = 0; h < 8; ++h) sum += expf(loc[h] - m);
  for (int off = 32; off; off >>= 1) sum += __shfl_down(sum, off);
  __syncthreads();
  if ((tid & 63) == 0) ps[tid >> 6] = sum;
  __syncthreads();
  if (tid == 0) sh_s = ps[0]+ps[1]+ps[2]+ps[3];
  __syncthreads();
  const float inv = 1.0f / sh_s;
#pragma unroll
  for (int h = 0; h < 8; ++h) attw[(size_t)p*NB + tid + h*256] = expf(loc[h] - m) * inv;
}

__global__ __launch_bounds__(256)
void zatt_kernel(const float* __restrict__ prev, const float* __restrict__ attw,
                 const float* __restrict__ lam, float* __restrict__ Z) {
  const int b = blockIdx.x, tid = threadIdx.x;
  __shared__ float w[8];
  if (tid < 8) w[tid] = attw[(size_t)tid*NB + b];
  __syncthreads();
  const float l2 = lam[0];
#pragma unroll
  for (int h = 0; h < 2; ++h) {
    int i = (tid + h*256) * 4;
    float4 acc = {0.f,0.f,0.f,0.f};
#pragma unroll
    for (int p = 0; p < 8; ++p) {
      float4 pv = *(const float4*)&prev[((size_t)p*NB + b)*DD + i];
      float wp = w[p];
      acc.x += wp * fminf(fmaxf(pv.x, -150.f), 150.f);
      acc.y += wp * fminf(fmaxf(pv.y, -150.f), 150.f);
      acc.z += wp * fminf(fmaxf(pv.z, -150.f), 150.f);
      acc.w += wp * fminf(fmaxf(pv.w, -150.f), 150.f);
    }
    acc.x *= l2; acc.y *= l2; acc.z *= l2; acc.w *= l2;
    *(float4*)&Z[(size_t)b*DD + i] = acc;
  }
}

__global__ __launch_bounds__(256)
void norm_kernel(float* __restrict__ mD) {
  const int tid = threadIdx.x;
  float v[4]; float mn = 3.4e38f, mx = -3.4e38f;
#pragma unroll
  for (int h = 0; h < 4; ++h) {
    v[h] = mD[tid + h*256];
    mn = fminf(mn, v[h]); mx = fmaxf(mx, v[h]);
  }
  for (int off = 32; off; off >>= 1) {
    mn = fminf(mn, __shfl_down(mn, off));
    mx = fmaxf(mx, __shfl_down(mx, off));
  }
  __shared__ float pmn[4], pmx[4]; __shared__ float smn, smx;
  if ((tid & 63) == 0) { pmn[tid>>6] = mn; pmx[tid>>6] = mx; }
  __syncthreads();
  if (tid == 0) {
    smn = fminf(fminf(pmn[0],pmn[1]), fminf(pmn[2],pmn[3]));
    smx = fmaxf(fmaxf(pmx[0],pmx[1]), fmaxf(pmx[2],pmx[3]));
  }
  __syncthreads();
  const float d = smx - smn + 1e-8f;
#pragma unroll
  for (int h = 0; h < 4; ++h) mD[tid + h*256] = (v[h] - smn) / d;
}

// ----------------------------------------------------------------- launcher
extern "C" void kernel_launch(void* const* d_in, const int* in_sizes, int n_in,
                              void* d_out, int out_size, void* d_ws, size_t ws_size,
                              hipStream_t stream) {
  const float* x    = (const float*)d_in[0];   // (2048, 2048)
  const float* prev = (const float*)d_in[1];   // (8, 2048, 2048)
  const float* Wd   = (const float*)d_in[2];   // (2048, 2048)
  const float* S    = (const float*)d_in[3];   // (2048, 2048) symmetric
  const float* lam  = (const float*)d_in[4];   // scalar

  float* out   = (float*)d_out;
  float* mD    = out;                 // 1024
  float* zlast = out + 1024;          // dense z_last; doubles as U scratch early

  float* B  = (float*)d_ws;                       // 16 MB
  float* C  = B  + (1u << 22);                    // 16 MB
  float* X1 = C  + (1u << 22);                    // 16 MB (s_t, then z_att)
  unsigned* sidx = (unsigned*)(X1 + (1u << 22));
  float*    sval = (float*)(sidx + 2048*64);
  int*      scnt = (int*)(sval + 2048*64);
  float*    att  = (float*)(scnt + 2048);
  float*    attw = att + 8*2048;
  unsigned short* PA = (unsigned short*)(attw + 8*2048);  // 3 planes, 25.2 MB
  unsigned short* PB = PA + (3u << 22);                   // 3 planes, 25.2 MB
  float* U = zlast;

  const dim3 gSp(8, NB);              // slice-major: linear id % 8 = slice = XCD
  const dim3 gT(64, 64);

  // split x and Wd into bf16 planes; B = x @ Wd^T on the matrix cores
  conv3<<<2048, 256, 0, stream>>>(x,  PA, PA + (1u<<22), PA + (2u<<22));
  conv3<<<2048, 256, 0, stream>>>(Wd, PB, PB + (1u<<22), PB + (2u<<22));
  gemm_bf6<0><<<512, 256, 0, stream>>>(PA, PB, nullptr, B);
  // z1 = hard_thr(B)
  topk_kernel<<<NB, 64, 0, stream>>>(B, sidx, sval, scnt, nullptr, nullptr, 0);
  // C = B + S z1   (XCD-sliced gather)
  spapply_sl<1><<<gSp, 64, 0, stream>>>(S, B, C, sidx, sval, scnt);
  // z2 = hard_thr(C)
  topk_kernel<<<NB, 64, 0, stream>>>(C, sidx, sval, scnt, nullptr, nullptr, 0);
  // s_t = Wd^T z2  (sparse rows of Wd, sliced)
  spapply_sl<0><<<gSp, 64, 0, stream>>>(Wd, nullptr, X1, sidx, sval, scnt);
  // u = s_t @ Wd : A-planes from s_t, B-planes = (Wd^T) via transposing split
  conv3<<<2048, 256, 0, stream>>>(X1, PA, PA + (1u<<22), PA + (2u<<22));
  tconv3<<<gT, 256, 0, stream>>>(Wd, PB, PB + (1u<<22), PB + (2u<<22));
  gemm_bf6<0><<<512, 256, 0, stream>>>(PA, PB, nullptr, U);
  // att[p,b] = <prev[p,b,:], u[b,:]>
  attdot_kernel<<<dim3(NB, 8), 256, 0, stream>>>(prev, U, att);
  softmax_kernel<<<8, 256, 0, stream>>>(att, attw);
  // z_att = lambda2 * sum_p attw * clip(prev)
  zatt_kernel<<<NB, 256, 0, stream>>>(prev, attw, lam, X1);
  // iter 1 (dense z): C = B + z_att @ S  (S symmetric -> planes as-is)
  conv3<<<2048, 256, 0, stream>>>(X1, PA, PA + (1u<<22), PA + (2u<<22));
  conv3<<<2048, 256, 0, stream>>>(S,  PB, PB + (1u<<22), PB + (2u<<22));
  gemm_bf6<1><<<512, 256, 0, stream>>>(PA, PB, B, C);
  topk_kernel<<<NB, 64, 0, stream>>>(C, sidx, sval, scnt, nullptr, nullptr, 0);
  // it 1..9: sliced gather + threshold; final emits dense z_last + mD
  for (int it = 1; it < 10; ++it) {
    spapply_sl<1><<<gSp, 64, 0, stream>>>(S, B, C, sidx, sval, scnt);
    const int fin = (it == 9);
    if (fin) hipMemsetAsync(mD, 0, 1024 * sizeof(float), stream);
    topk_kernel<<<NB, 64, 0, stream>>>(C, sidx, sval, scnt,
                                       fin ? zlast : nullptr,
                                       fin ? mD : nullptr, fin);
  }
  // mD_norm = (mD - min) / (max - min + 1e-8)
  norm_kernel<<<1, 256, 0, stream>>>(mD);
}

// Round 2
// 1220.615 us; speedup vs baseline: 1.3664x; 1.2967x over previous
//
#include <hip/hip_runtime.h>

// DUST_65085934403760 : LIHT sparse-coding + window attention, MI355X.
// Round 9: fix the round-8 staging catastrophe. gemm_bf6's global_load_lds
// lanes read 16B at 4KB stride (row-major planes, 64B-wide K-chunk) -> 64
// cache lines per wave-load, FETCH 207MB/dispatch, 8.6K cyc/chunk.
//  - bf16 planes now stored in GEMM-READY TILED layout: per (tile, K-chunk)
//    the sub-block is contiguous, internal order == the LDS layout the frag
//    reads expect ([g][row]*16B). Every global_load_lds is a contiguous 1KB.
//  - conv3T<128> (A-operands), conv3T<64> (B-operands), tconv3 (Wd^T) do the
//    split + layout transform via LDS; memory-bound ~10us passes.
//  - gemm_bf6 fragment addressing, MFMA order, sync structure UNCHANGED ->
//    bit-identical numerics to round 8 (absmax 0.015625).
//  - All non-GEMM kernels are the proven round-3/7 versions, verbatim.

#define DD 2048
#define NB 2048
#define PLANE ((size_t)1 << 22)   // elements per bf16 plane (2048*2048)

using short8v  = __attribute__((ext_vector_type(8))) short;
using ushort8v = __attribute__((ext_vector_type(8))) unsigned short;
using ushort4v = __attribute__((ext_vector_type(4))) unsigned short;
using float4v  = __attribute__((ext_vector_type(4))) float;

// ---------------------------------------------------------------- helpers
__device__ __forceinline__ unsigned short f2bf(float f) {
  unsigned u = __float_as_uint(f);
  u = u + 0x7fffu + ((u >> 16) & 1u);
  return (unsigned short)(u >> 16);
}
__device__ __forceinline__ float bf2f(unsigned short h) {
  return __uint_as_float((unsigned)h << 16);
}
__device__ __forceinline__ void gload16(const void* g, void* l) {
  __builtin_amdgcn_global_load_lds((const __attribute__((address_space(1))) void*)g,
                                   (__attribute__((address_space(3))) void*)l,
                                   16, 0, 0);
}

// ---------------------------------------------- fp32 -> 3 tiled bf16 planes
// Tiled plane layout (R = tile rows, 128 for A-operands / 64 for B-operands):
//   plane base + ((rt*64 + c) * R*32) + g*(R*8) + r*8 + e   [elements]
// i.e. tile (rt,c) is R*32 contiguous elements whose byte order is exactly
// the GEMM LDS layout [g][r]*16B. gload of 1KB = 512 consecutive elements.
template<int R>
__global__ __launch_bounds__(256)
void conv3T(const float* __restrict__ in, unsigned short* __restrict__ p0,
            unsigned short* __restrict__ p1, unsigned short* __restrict__ p2) {
  __shared__ unsigned short lds3[3][4][R][8];
  const int rt = blockIdx.x, c = blockIdx.y, t = threadIdx.x;
  const int cf = (t & 7) * 4;           // k-offset within chunk, {0,4,...,28}
  const int g = cf >> 3, e0 = cf & 7;   // e0 in {0,4}
#pragma unroll
  for (int pass = 0; pass < R / 32; ++pass) {
    const int r = pass * 32 + (t >> 3);
    float4 v = *(const float4*)(in + (size_t)(rt * R + r) * DD + c * 32 + cf);
    float vv[4] = {v.x, v.y, v.z, v.w};
    ushort4v o0, o1, o2;
#pragma unroll
    for (int j = 0; j < 4; ++j) {
      unsigned short a0 = f2bf(vv[j]); float r1 = vv[j] - bf2f(a0);
      unsigned short a1 = f2bf(r1);    float r2 = r1 - bf2f(a1);
      unsigned short a2 = f2bf(r2);
      o0[j] = a0; o1[j] = a1; o2[j] = a2;
    }
    *(ushort4v*)&lds3[0][g][r][e0] = o0;
    *(ushort4v*)&lds3[1][g][r][e0] = o1;
    *(ushort4v*)&lds3[2][g][r][e0] = o2;
  }
  __syncthreads();
  const ushort8v* src = (const ushort8v*)lds3;   // 12R units of 16B
  const size_t tb = ((size_t)rt * 64 + c) * (R * 32);
#pragma unroll
  for (int w = 0; w < (3 * R) / 64; ++w) {
    const int idx = w * 256 + t;
    const int p = idx / (4 * R), off = idx % (4 * R);
    unsigned short* dst = (p == 0 ? p0 : p == 1 ? p1 : p2) + tb + (size_t)off * 8;
    *(ushort8v*)dst = src[idx];
  }
}

// ------------------------- transposing split: tiled B-planes of in^T (R=64)
// B'[n,k] = in[k,n]; output layout identical to conv3T<64>'s.
__global__ __launch_bounds__(256)
void tconv3(const float* __restrict__ in, unsigned short* __restrict__ p0,
            unsigned short* __restrict__ p1, unsigned short* __restrict__ p2) {
  __shared__ unsigned short lds3[3][4][64][8];
  const int nt = blockIdx.x, c = blockIdx.y, t = threadIdx.x;
  const int nf = (t & 15) * 4;
#pragma unroll
  for (int pass = 0; pass < 2; ++pass) {
    const int kr = pass * 16 + (t >> 4);
    float4 v = *(const float4*)(in + (size_t)(c * 32 + kr) * DD + nt * 64 + nf);
    float vv[4] = {v.x, v.y, v.z, v.w};
    const int g = kr >> 3, e = kr & 7;
#pragma unroll
    for (int j = 0; j < 4; ++j) {
      unsigned short a0 = f2bf(vv[j]); float r1 = vv[j] - bf2f(a0);
      unsigned short a1 = f2bf(r1);    float r2 = r1 - bf2f(a1);
      unsigned short a2 = f2bf(r2);
      lds3[0][g][nf + j][e] = a0;
      lds3[1][g][nf + j][e] = a1;
      lds3[2][g][nf + j][e] = a2;
    }
  }
  __syncthreads();
  const ushort8v* src = (const ushort8v*)lds3;   // 768 units of 16B
  const size_t tb = ((size_t)nt * 64 + c) * 2048;
#pragma unroll
  for (int w = 0; w < 3; ++w) {
    const int idx = w * 256 + t;
    const int p = idx >> 8, off = idx & 255;
    unsigned short* dst = (p == 0 ? p0 : p == 1 ? p1 : p2) + tb + (size_t)off * 8;
    *(ushort8v*)dst = src[idx];
  }
}

// --------------------------------------------------- bf16x6 MFMA GEMM
// C[m,n] = sum_k A[m,k]*B'[n,k]  (+ Cadd[m,n]), A/B' given as 3 TILED bf16
// planes. Tile 128(m) x 64(n), K-chunk 32, 4 waves, mfma_f32_16x16x32_bf16.
// LDS per buffer: A 3*8KB = 24KB, B 3*4KB = 12KB.
#define LDS_B_OFF 24576
#define LDS_BUF   36864

template<int ADD>
__global__ __launch_bounds__(256, 2)
void gemm_bf6(const unsigned short* __restrict__ PA,
              const unsigned short* __restrict__ PB,
              const float* __restrict__ Cadd, float* __restrict__ Cout) {
  __shared__ char lds[2 * LDS_BUF];
  const int tid = threadIdx.x, lane = tid & 63, wid = tid >> 6;

  // XCD-chunked swizzle (bijective, 512 % 8 == 0): XCD x gets 2 full m-rows;
  // its A-panel slice (3MB) stays resident in the XCD's 4MB L2.
  int lin = (int)blockIdx.x;
  lin = (lin & 7) * 64 + (lin >> 3);
  const int m0 = (lin >> 5) * 128;
  const int n0 = (lin & 31) * 64;

  // Coalesced staging: each gload16 reads a contiguous 1KB of a tiled plane
  // and writes linear LDS; plane-internal order == LDS layout, no permute.
  auto stage = [&](char* base, int c) {
    const size_t at = ((size_t)(m0 >> 7) * 64 + c) * 4096;
    const size_t bt = ((size_t)(n0 >> 6) * 64 + c) * 2048;
#pragma unroll
    for (int i = 0; i < 6; ++i) {               // A: 24 wave-loads of 1KB
      const int tA = wid * 6 + i, p = tA >> 3, j = tA & 7;
      gload16(PA + p * PLANE + at + j * 512 + lane * 8,
              base + p * 8192 + j * 1024 + lane * 16);
    }
#pragma unroll
    for (int i = 0; i < 3; ++i) {               // B: 12 wave-loads of 1KB
      const int tB = wid * 3 + i, p = tB >> 2, j = tB & 3;
      gload16(PB + p * PLANE + bt + j * 512 + lane * 8,
              base + LDS_B_OFF + p * 4096 + j * 1024 + lane * 16);
    }
  };

  float4v acc[4][2] = {};

  // wave -> 64x32 output sub-tile; frag addressing (K-grouped LDS layout):
  // lanes 0..15 hit consecutive 16B units -> bank-uniform ds_read_b128.
  const int rsel = (wid >> 1) * 64;
  const int csel = (wid & 1) * 32;
  const int g16  = lane >> 4;
  const int l15  = lane & 15;
  const int aoff = g16 * 2048 + (rsel + l15) * 16;              // + p*8192 + mg*256
  const int boff = LDS_B_OFF + g16 * 1024 + (csel + l15) * 16;  // + p*4096 + ng*256

  stage(lds, 0);
  __syncthreads();

  for (int c = 0; c < 64; ++c) {
    char* cur = lds + (c & 1) * LDS_BUF;
    if (c < 63) stage(lds + ((c & 1) ^ 1) * LDS_BUF, c + 1);

    short8v b0[2], b1[2], b2[2];
#pragma unroll
    for (int ng = 0; ng < 2; ++ng) {
      b0[ng] = *(const short8v*)(cur + boff + 0 * 4096 + ng * 256);
      b1[ng] = *(const short8v*)(cur + boff + 1 * 4096 + ng * 256);
      b2[ng] = *(const short8v*)(cur + boff + 2 * 4096 + ng * 256);
    }
#pragma unroll
    for (int mg = 0; mg < 4; ++mg) {
      const short8v a0 = *(const short8v*)(cur + 0 * 8192 + aoff + mg * 256);
      const short8v a1 = *(const short8v*)(cur + 1 * 8192 + aoff + mg * 256);
      const short8v a2 = *(const short8v*)(cur + 2 * 8192 + aoff + mg * 256);
#pragma unroll
      for (int ng = 0; ng < 2; ++ng) {
        float4v t = acc[mg][ng];
        t = __builtin_amdgcn_mfma_f32_16x16x32_bf16(a0, b0[ng], t, 0, 0, 0); // h1*h1
        t = __builtin_amdgcn_mfma_f32_16x16x32_bf16(a0, b1[ng], t, 0, 0, 0); // h1*h2
        t = __builtin_amdgcn_mfma_f32_16x16x32_bf16(a1, b0[ng], t, 0, 0, 0); // h2*h1
        t = __builtin_amdgcn_mfma_f32_16x16x32_bf16(a1, b1[ng], t, 0, 0, 0); // h2*h2
        t = __builtin_amdgcn_mfma_f32_16x16x32_bf16(a0, b2[ng], t, 0, 0, 0); // h1*h3
        t = __builtin_amdgcn_mfma_f32_16x16x32_bf16(a2, b0[ng], t, 0, 0, 0); // h3*h1
        acc[mg][ng] = t;
      }
    }
    __syncthreads();   // drains vmcnt (next buffer ready) + read-done fence
  }

  // C/D layout (m89-verified): col = lane&15, row = (lane>>4)*4 + reg.
  const int row0 = m0 + rsel + g16 * 4;
  const int col0 = n0 + csel + l15;
#pragma unroll
  for (int mg = 0; mg < 4; ++mg)
#pragma unroll
    for (int ng = 0; ng < 2; ++ng)
#pragma unroll
      for (int r = 0; r < 4; ++r) {
        const size_t o = (size_t)(row0 + mg * 16 + r) * DD + col0 + ng * 16;
        float v = acc[mg][ng][r];
        if (ADD) v += Cadd[o];
        Cout[o] = v;
      }
}

// ------------------------------------ XCD-sliced sparse apply (1 wave/block)
template<int HASBASE>
__global__ __launch_bounds__(64)
void spapply_sl(const float* __restrict__ M, const float* __restrict__ baseB,
                float* __restrict__ outF, const unsigned* __restrict__ sidx,
                const float* __restrict__ sval, const int* __restrict__ scnt) {
  const int b = blockIdx.y, lane = threadIdx.x;
  const int col = blockIdx.x * 256 + lane * 4;
  const int nc = scnt[b];
  const unsigned* ip = sidx + b * 64;
  const float* vp = sval + b * 64;
  const size_t ro = (size_t)b * DD + col;
  float4 a;
  if (HASBASE) a = *(const float4*)&baseB[ro];
  else         a = make_float4(0.f, 0.f, 0.f, 0.f);
  for (int t = 0; t < nc; ++t) {
    const unsigned j = ip[t];
    const float v = vp[t];
    float4 m = *(const float4*)&M[(size_t)j * DD + col];
    a.x = fmaf(v, m.x, a.x); a.y = fmaf(v, m.y, a.y);
    a.z = fmaf(v, m.z, a.z); a.w = fmaf(v, m.w, a.w);
  }
  *(float4*)&outF[ro] = a;
}

// ------------------------------------------------------------ top-k (1 wave)
__global__ __launch_bounds__(64)
void topk_kernel(const float* __restrict__ src, unsigned* __restrict__ sidx,
                 float* __restrict__ sval, int* __restrict__ scnt,
                 float* __restrict__ dense, float* __restrict__ mD,
                 int finalMode) {
  const int b = blockIdx.x;
  const int lane = threadIdx.x;
  const float* row = src + (size_t)b * DD;
  float v[32]; unsigned ab[32];
#pragma unroll
  for (int e4 = 0; e4 < 8; ++e4) {
    float4 t = *(const float4*)&row[e4*256 + lane*4];
    v[e4*4+0]=t.x; v[e4*4+1]=t.y; v[e4*4+2]=t.z; v[e4*4+3]=t.w;
  }
#pragma unroll
  for (int e = 0; e < 32; ++e) ab[e] = __float_as_uint(v[e]) & 0x7fffffffu;

  unsigned mxb = 0;
#pragma unroll
  for (int e = 0; e < 32; ++e) mxb = ab[e] > mxb ? ab[e] : mxb;
  for (int off = 32; off; off >>= 1) {
    unsigned o = (unsigned)__shfl_down((int)mxb, off);
    mxb = o > mxb ? o : mxb;
  }
  mxb = (unsigned)__shfl((int)mxb, 0);
  const int emax = (int)(mxb >> 23);

  int eStar = 0, cntAbove = 0;
  {
    int prevc = 0;
    for (int e = emax; e >= 0; --e) {
      unsigned T = ((unsigned)e) << 23;
      int c = 0;
#pragma unroll
      for (int k = 0; k < 32; ++k) c += (ab[k] >= T) ? 1 : 0;
      for (int off = 32; off; off >>= 1) c += __shfl_down(c, off);
      c = __shfl(c, 0);
      if (c >= 50) { eStar = e; cntAbove = prevc; break; }
      prevc = c;
    }
  }
  unsigned kth = ((unsigned)eStar) << 23;
  int kneed = 50 - cntAbove;

  __shared__ int hist[256];
  __shared__ int sh_sel, sh_kneed;
  for (int p = 0; p < 3; ++p) {
    const unsigned mask = (p==0) ? 0x7F800000u : (p==1) ? 0x7FFF8000u : 0x7FFFFF80u;
    const int sh = (p==0) ? 15 : (p==1) ? 7 : 0;
    for (int t = lane; t < 256; t += 64) hist[t] = 0;
    __syncthreads();
#pragma unroll
    for (int e = 0; e < 32; ++e)
      if ((ab[e] & mask) == kth) atomicAdd(&hist[(ab[e] >> sh) & 0xFF], 1);
    __syncthreads();
    int h0 = hist[lane*4+0], h1 = hist[lane*4+1], h2 = hist[lane*4+2], h3 = hist[lane*4+3];
    int s = h0 + h1 + h2 + h3;
    int x = s;
    for (int off = 1; off < 64; off <<= 1) {
      int y = __shfl_down(x, off);
      if (lane + off < 64) x += y;
    }
    int excl = x - s;
    int c3 = excl + h3, c2 = c3 + h2, c1 = c2 + h1, c0 = c1 + h0;
    if (c0 >= kneed && c1   < kneed) { sh_sel = lane*4+0; sh_kneed = kneed - c1;  }
    if (c1 >= kneed && c2   < kneed) { sh_sel = lane*4+1; sh_kneed = kneed - c2;  }
    if (c2 >= kneed && c3   < kneed) { sh_sel = lane*4+2; sh_kneed = kneed - c3;  }
    if (c3 >= kneed && excl < kneed) { sh_sel = lane*4+3; sh_kneed = kneed - excl;}
    __syncthreads();
    kth |= ((unsigned)sh_sel) << sh;
    kneed = sh_kneed;
    __syncthreads();
  }

  int base = 0;
#pragma unroll
  for (int e4 = 0; e4 < 8; ++e4) {
    float o[4];
#pragma unroll
    for (int qq = 0; qq < 4; ++qq) {
      const int e = e4*4 + qq;
      const bool sel = ab[e] >= kth;
      unsigned long long msk = __ballot(sel);
      int pre = __popcll(msk & ((1ull << lane) - 1ull));
      const unsigned gi = (unsigned)(e4*256 + lane*4 + qq);
      if (sel) {
        int slot = base + pre;
        if (slot < 64) { sidx[b*64+slot] = gi; sval[b*64+slot] = v[e]; }
        if (finalMode) atomicAdd(&mD[gi & 1023u], v[e]*v[e]);
      }
      base += __popcll(msk);
      o[qq] = sel ? v[e] : 0.f;
    }
    if (finalMode) {
      float4 t = {o[0],o[1],o[2],o[3]};
      *(float4*)&dense[(size_t)b*DD + e4*256 + lane*4] = t;
    }
  }
  if (lane == 0) scnt[b] = base < 64 ? base : 64;
}

// ------------------------------------------------------------- attention bits
__global__ __launch_bounds__(256)
void attdot_kernel(const float* __restrict__ prev, const float* __restrict__ U,
                   float* __restrict__ att) {
  const int b = blockIdx.x, p = blockIdx.y, tid = threadIdx.x;
  const float* pr = prev + ((size_t)p*NB + b) * DD;
  const float* u  = U + (size_t)b * DD;
  float s = 0.f;
#pragma unroll
  for (int h = 0; h < 2; ++h) {
    int i = (tid + h*256) * 4;
    float4 a = *(const float4*)&pr[i];
    float4 c = *(const float4*)&u[i];
    s += a.x*c.x + a.y*c.y + a.z*c.z + a.w*c.w;
  }
  for (int off = 32; off; off >>= 1) s += __shfl_down(s, off);
  __shared__ float ps[4];
  if ((tid & 63) == 0) ps[tid >> 6] = s;
  __syncthreads();
  if (tid == 0) att[(size_t)p*NB + b] = ps[0]+ps[1]+ps[2]+ps[3];
}

__global__ __launch_bounds__(256)
void softmax_kernel(const float* __restrict__ att, float* __restrict__ attw) {
  const int p = blockIdx.x, tid = threadIdx.x;
  const float* a = att + (size_t)p*NB;
  float loc[8]; float mx = -3.4e38f;
#pragma unroll
  for (int h = 0; h < 8; ++h) { loc[h] = a[tid + h*256]; mx = fmaxf(mx, loc[h]); }
  for (int off = 32; off; off >>= 1) mx = fmaxf(mx, __shfl_down(mx, off));
  __shared__ float ps[4]; __shared__ float sh_m, sh_s;
  if ((tid & 63) == 0) ps[tid >> 6] = mx;
  __syncthreads();
  if (tid == 0) sh_m = fmaxf(fmaxf(ps[0],ps[1]), fmaxf(ps[2],ps[3]));
  __syncthreads();
  const float m = sh_m;
  float sum = 0.f;
#pragma unroll
  for (int h = 0; h < 8; ++h) sum += expf(loc[h] - m);
  for (int off = 32; off; off >>= 1) sum += __shfl_down(sum, off);
  __syncthreads();
  if ((tid & 63) == 0) ps[tid >> 6] = sum;
  __syncthreads();
  if (tid == 0) sh_s = ps[0]+ps[1]+ps[2]+ps[3];
  __syncthreads();
  const float inv = 1.0f / sh_s;
#pragma unroll
  for (int h = 0; h < 8; ++h) attw[(size_t)p*NB + tid + h*256] = expf(loc[h] - m) * inv;
}

__global__ __launch_bounds__(256)
void zatt_kernel(const float* __restrict__ prev, const float* __restrict__ attw,
                 const float* __restrict__ lam, float* __restrict__ Z) {
  const int b = blockIdx.x, tid = threadIdx.x;
  __shared__ float w[8];
  if (tid < 8) w[tid] = attw[(size_t)tid*NB + b];
  __syncthreads();
  const float l2 = lam[0];
#pragma unroll
  for (int h = 0; h < 2; ++h) {
    int i = (tid + h*256) * 4;
    float4 acc = {0.f,0.f,0.f,0.f};
#pragma unroll
    for (int p = 0; p < 8; ++p) {
      float4 pv = *(const float4*)&prev[((size_t)p*NB + b)*DD + i];
      float wp = w[p];
      acc.x += wp * fminf(fmaxf(pv.x, -150.f), 150.f);
      acc.y += wp * fminf(fmaxf(pv.y, -150.f), 150.f);
      acc.z += wp * fminf(fmaxf(pv.z, -150.f), 150.f);
      acc.w += wp * fminf(fmaxf(pv.w, -150.f), 150.f);
    }
    acc.x *= l2; acc.y *= l2; acc.z *= l2; acc.w *= l2;
    *(float4*)&Z[(size_t)b*DD + i] = acc;
  }
}

__global__ __launch_bounds__(256)
void norm_kernel(float* __restrict__ mD) {
  const int tid = threadIdx.x;
  float v[4]; float mn = 3.4e38f, mx = -3.4e38f;
#pragma unroll
  for (int h = 0; h < 4; ++h) {
    v[h] = mD[tid + h*256];
    mn = fminf(mn, v[h]); mx = fmaxf(mx, v[h]);
  }
  for (int off = 32; off; off >>= 1) {
    mn = fminf(mn, __shfl_down(mn, off));
    mx = fmaxf(mx, __shfl_down(mx, off));
  }
  __shared__ float pmn[4], pmx[4]; __shared__ float smn, smx;
  if ((tid & 63) == 0) { pmn[tid>>6] = mn; pmx[tid>>6] = mx; }
  __syncthreads();
  if (tid == 0) {
    smn = fminf(fminf(pmn[0],pmn[1]), fminf(pmn[2],pmn[3]));
    smx = fmaxf(fmaxf(pmx[0],pmx[1]), fmaxf(pmx[2],pmx[3]));
  }
  __syncthreads();
  const float d = smx - smn + 1e-8f;
#pragma unroll
  for (int h = 0; h < 4; ++h) mD[tid + h*256] = (v[h] - smn) / d;
}

// ----------------------------------------------------------------- launcher
extern "C" void kernel_launch(void* const* d_in, const int* in_sizes, int n_in,
                              void* d_out, int out_size, void* d_ws, size_t ws_size,
                              hipStream_t stream) {
  const float* x    = (const float*)d_in[0];   // (2048, 2048)
  const float* prev = (const float*)d_in[1];   // (8, 2048, 2048)
  const float* Wd   = (const float*)d_in[2];   // (2048, 2048)
  const float* S    = (const float*)d_in[3];   // (2048, 2048) symmetric
  const float* lam  = (const float*)d_in[4];   // scalar

  float* out   = (float*)d_out;
  float* mD    = out;                 // 1024
  float* zlast = out + 1024;          // dense z_last; doubles as U scratch early

  float* B  = (float*)d_ws;                       // 16 MB
  float* C  = B  + (1u << 22);                    // 16 MB
  float* X1 = C  + (1u << 22);                    // 16 MB (s_t, then z_att)
  unsigned* sidx = (unsigned*)(X1 + (1u << 22));
  float*    sval = (float*)(sidx + 2048*64);
  int*      scnt = (int*)(sval + 2048*64);
  float*    att  = (float*)(scnt + 2048);
  float*    attw = att + 8*2048;
  unsigned short* PA = (unsigned short*)(attw + 8*2048);  // 3 planes, 25.2 MB
  unsigned short* PB = PA + 3 * PLANE;                    // 3 planes, 25.2 MB
  float* U = zlast;

  const dim3 gSp(8, NB);              // slice-major: linear id % 8 = slice = XCD
  const dim3 gA(16, 64);              // conv3T<128>: (m-tile, k-chunk)
  const dim3 gB(32, 64);              // conv3T<64> / tconv3: (n-tile, k-chunk)

  // split x and Wd into tiled bf16 planes; B = x @ Wd^T on the matrix cores
  conv3T<128><<<gA, 256, 0, stream>>>(x,  PA, PA + PLANE, PA + 2*PLANE);
  conv3T<64> <<<gB, 256, 0, stream>>>(Wd, PB, PB + PLANE, PB + 2*PLANE);
  gemm_bf6<0><<<512, 256, 0, stream>>>(PA, PB, nullptr, B);
  // z1 = hard_thr(B)
  topk_kernel<<<NB, 64, 0, stream>>>(B, sidx, sval, scnt, nullptr, nullptr, 0);
  // C = B + S z1   (XCD-sliced gather)
  spapply_sl<1><<<gSp, 64, 0, stream>>>(S, B, C, sidx, sval, scnt);
  // z2 = hard_thr(C)
  topk_kernel<<<NB, 64, 0, stream>>>(C, sidx, sval, scnt, nullptr, nullptr, 0);
  // s_t = Wd^T z2  (sparse rows of Wd, sliced)
  spapply_sl<0><<<gSp, 64, 0, stream>>>(Wd, nullptr, X1, sidx, sval, scnt);
  // u = s_t @ Wd : A-planes from s_t, B-planes = (Wd^T) via transposing split
  conv3T<128><<<gA, 256, 0, stream>>>(X1, PA, PA + PLANE, PA + 2*PLANE);
  tconv3<<<gB, 256, 0, stream>>>(Wd, PB, PB + PLANE, PB + 2*PLANE);
  gemm_bf6<0><<<512, 256, 0, stream>>>(PA, PB, nullptr, U);
  // att[p,b] = <prev[p,b,:], u[b,:]>
  attdot_kernel<<<dim3(NB, 8), 256, 0, stream>>>(prev, U, att);
  softmax_kernel<<<8, 256, 0, stream>>>(att, attw);
  // z_att = lambda2 * sum_p attw * clip(prev)
  zatt_kernel<<<NB, 256, 0, stream>>>(prev, attw, lam, X1);
  // iter 1 (dense z): C = B + z_att @ S  (S symmetric -> row-major == B'[n,k])
  conv3T<128><<<gA, 256, 0, stream>>>(X1, PA, PA + PLANE, PA + 2*PLANE);
  conv3T<64> <<<gB, 256, 0, stream>>>(S,  PB, PB + PLANE, PB + 2*PLANE);
  gemm_bf6<1><<<512, 256, 0, stream>>>(PA, PB, B, C);
  topk_kernel<<<NB, 64, 0, stream>>>(C, sidx, sval, scnt, nullptr, nullptr, 0);
  // it 1..9: sliced gather + threshold; final emits dense z_last + mD
  for (int it = 1; it < 10; ++it) {
    spapply_sl<1><<<gSp, 64, 0, stream>>>(S, B, C, sidx, sval, scnt);
    const int fin = (it == 9);
    if (fin) hipMemsetAsync(mD, 0, 1024 * sizeof(float), stream);
    topk_kernel<<<NB, 64, 0, stream>>>(C, sidx, sval, scnt,
                                       fin ? zlast : nullptr,
                                       fin ? mD : nullptr, fin);
  }
  // mD_norm = (mD - min) / (max - min + 1e-8)
  norm_kernel<<<1, 256, 0, stream>>>(mD);
}

// Round 3
// 1218.292 us; speedup vs baseline: 1.3690x; 1.0019x over previous
//
#include <hip/hip_runtime.h>

// DUST_65085934403760 : LIHT sparse-coding + window attention, MI355X.
// Round 10: gemm_bf6 v3 — kill the per-chunk vmcnt(0) drain (round-9 analysis:
// MFMA 1862cy + LDS 1728cy ~= wall 3562cy per CU-chunk -> pipes don't overlap).
//  - Triple-buffered K-chunks, counted s_waitcnt vmcnt(12) (never 0 in the
//    main loop; 2 chunks x 6 loads/wave in flight), raw s_barrier pairs,
//    sched_barrier(0) fences (guide rule #18).
//  - Tile 128x128, 512 threads (8 waves), wave-tile 64x32 (4mg x 2ng of
//    16x16x32): halves LDS traffic per output vs round 9. LDS 3x48KB=144KB.
//  - 2D XCD map (4m x 8n per XCD): per-XCD fetch 28 -> 19 MB.
//  - MFMA order per accumulator unchanged -> bit-identical numerics.
//  - conv/topk/spapply/attention kernels: proven versions, verbatim.

#define DD 2048
#define NB 2048
#define PLANE ((size_t)1 << 22)   // elements per bf16 plane (2048*2048)
#define ZONE 49152                // LDS bytes per chunk zone (A 24K + B 24K)

using short8v  = __attribute__((ext_vector_type(8))) short;
using ushort8v = __attribute__((ext_vector_type(8))) unsigned short;
using ushort4v = __attribute__((ext_vector_type(4))) unsigned short;
using float4v  = __attribute__((ext_vector_type(4))) float;

// ---------------------------------------------------------------- helpers
__device__ __forceinline__ unsigned short f2bf(float f) {
  unsigned u = __float_as_uint(f);
  u = u + 0x7fffu + ((u >> 16) & 1u);
  return (unsigned short)(u >> 16);
}
__device__ __forceinline__ float bf2f(unsigned short h) {
  return __uint_as_float((unsigned)h << 16);
}
__device__ __forceinline__ void gload16(const void* g, void* l) {
  __builtin_amdgcn_global_load_lds((const __attribute__((address_space(1))) void*)g,
                                   (__attribute__((address_space(3))) void*)l,
                                   16, 0, 0);
}

// ---------------------------------------------- fp32 -> 3 tiled bf16 planes
// Tiled plane layout (R = tile rows, 128 for A-operands / 64 for B-operands):
//   plane base + ((rt*64 + c) * R*32) + g*(R*8) + r*8 + e   [elements]
template<int R>
__global__ __launch_bounds__(256)
void conv3T(const float* __restrict__ in, unsigned short* __restrict__ p0,
            unsigned short* __restrict__ p1, unsigned short* __restrict__ p2) {
  __shared__ unsigned short lds3[3][4][R][8];
  const int rt = blockIdx.x, c = blockIdx.y, t = threadIdx.x;
  const int cf = (t & 7) * 4;
  const int g = cf >> 3, e0 = cf & 7;
#pragma unroll
  for (int pass = 0; pass < R / 32; ++pass) {
    const int r = pass * 32 + (t >> 3);
    float4 v = *(const float4*)(in + (size_t)(rt * R + r) * DD + c * 32 + cf);
    float vv[4] = {v.x, v.y, v.z, v.w};
    ushort4v o0, o1, o2;
#pragma unroll
    for (int j = 0; j < 4; ++j) {
      unsigned short a0 = f2bf(vv[j]); float r1 = vv[j] - bf2f(a0);
      unsigned short a1 = f2bf(r1);    float r2 = r1 - bf2f(a1);
      unsigned short a2 = f2bf(r2);
      o0[j] = a0; o1[j] = a1; o2[j] = a2;
    }
    *(ushort4v*)&lds3[0][g][r][e0] = o0;
    *(ushort4v*)&lds3[1][g][r][e0] = o1;
    *(ushort4v*)&lds3[2][g][r][e0] = o2;
  }
  __syncthreads();
  const ushort8v* src = (const ushort8v*)lds3;
  const size_t tb = ((size_t)rt * 64 + c) * (R * 32);
#pragma unroll
  for (int w = 0; w < (3 * R) / 64; ++w) {
    const int idx = w * 256 + t;
    const int p = idx / (4 * R), off = idx % (4 * R);
    unsigned short* dst = (p == 0 ? p0 : p == 1 ? p1 : p2) + tb + (size_t)off * 8;
    *(ushort8v*)dst = src[idx];
  }
}

// ------------------------- transposing split: tiled B-planes of in^T (R=64)
__global__ __launch_bounds__(256)
void tconv3(const float* __restrict__ in, unsigned short* __restrict__ p0,
            unsigned short* __restrict__ p1, unsigned short* __restrict__ p2) {
  __shared__ unsigned short lds3[3][4][64][8];
  const int nt = blockIdx.x, c = blockIdx.y, t = threadIdx.x;
  const int nf = (t & 15) * 4;
#pragma unroll
  for (int pass = 0; pass < 2; ++pass) {
    const int kr = pass * 16 + (t >> 4);
    float4 v = *(const float4*)(in + (size_t)(c * 32 + kr) * DD + nt * 64 + nf);
    float vv[4] = {v.x, v.y, v.z, v.w};
    const int g = kr >> 3, e = kr & 7;
#pragma unroll
    for (int j = 0; j < 4; ++j) {
      unsigned short a0 = f2bf(vv[j]); float r1 = vv[j] - bf2f(a0);
      unsigned short a1 = f2bf(r1);    float r2 = r1 - bf2f(a1);
      unsigned short a2 = f2bf(r2);
      lds3[0][g][nf + j][e] = a0;
      lds3[1][g][nf + j][e] = a1;
      lds3[2][g][nf + j][e] = a2;
    }
  }
  __syncthreads();
  const ushort8v* src = (const ushort8v*)lds3;
  const size_t tb = ((size_t)nt * 64 + c) * 2048;
#pragma unroll
  for (int w = 0; w < 3; ++w) {
    const int idx = w * 256 + t;
    const int p = idx >> 8, off = idx & 255;
    unsigned short* dst = (p == 0 ? p0 : p == 1 ? p1 : p2) + tb + (size_t)off * 8;
    *(ushort8v*)dst = src[idx];
  }
}

// --------------------------------------------------- bf16x6 MFMA GEMM v3
// C[m,n] = sum_k A[m,k]*B'[n,k]  (+ Cadd[m,n]); 3 tiled bf16 planes each.
// Tile 128(m) x 128(n), K-chunk 32, 8 waves; wave = 64x32 (4mg x 2ng).
// Zone layout: A planes p*8192 ([g][128 r][16B]); B at 24576 + p*8192
// ([sub(2)][g][64 col][16B]).
template<int ADD>
__global__ __launch_bounds__(512)
void gemm_bf6(const unsigned short* __restrict__ PA,
              const unsigned short* __restrict__ PB,
              const float* __restrict__ Cadd, float* __restrict__ Cout) {
  __shared__ char lds[3 * ZONE];
  const int tid = threadIdx.x, lane = tid & 63, wid = tid >> 6;

  // 2D XCD map: 256 blocks = 16x16 tiles; XCD (xr,xc) covers 4m x 8n.
  const int lin = (int)blockIdx.x;
  const int xcd = lin & 7, q = lin >> 3;
  const int mt = (xcd >> 1) * 4 + (q >> 3);
  const int nt = (xcd & 1) * 8 + (q & 7);
  const int m0 = mt * 128, n0 = nt * 128;

  // stage chunk c into zone: 48 x 1KB loads, 6 per wave (w0-3: A, w4-7: B).
  auto stage = [&](char* base, int c) {
    if (wid < 4) {
      const size_t at = ((size_t)mt * 64 + c) * 4096;
#pragma unroll
      for (int i = 0; i < 6; ++i) {
        const int slot = wid * 6 + i, p = slot >> 3, j = slot & 7;
        gload16(PA + p * PLANE + at + j * 512 + lane * 8,
                base + p * 8192 + j * 1024 + lane * 16);
      }
    } else {
#pragma unroll
      for (int i = 0; i < 6; ++i) {
        const int b = (wid - 4) * 6 + i, p = b >> 3, r = b & 7;
        const int sub = r >> 2, j = r & 3;
        const size_t bt = ((size_t)(nt * 2 + sub) * 64 + c) * 2048;
        gload16(PB + p * PLANE + bt + j * 512 + lane * 8,
                base + 24576 + p * 8192 + sub * 4096 + j * 1024 + lane * 16);
      }
    }
  };

  float4v acc[4][2] = {};

  const int rsel = (wid >> 2) * 64;        // wave rows: 0 / 64
  const int csel = (wid & 3) * 32;         // wave cols: 0/32/64/96
  const int g16  = lane >> 4;
  const int l15  = lane & 15;
  const int aoff = g16 * 2048 + (rsel + l15) * 16;                 // + p*8192 + mg*256
  const int boff = 24576 + (csel >> 6) * 4096 + g16 * 1024
                 + ((csel & 32) + l15) * 16;                       // + p*8192 + ng*256

  stage(lds, 0);
  stage(lds + ZONE, 1);

  int zc = 0, zs = 2;
  for (int c = 0; c < 64; ++c) {
    if (c + 2 < 64) stage(lds + zs * ZONE, c + 2);
    // counted waits: steady state keeps 12 loads/wave in flight (chunks c+1,c+2)
    if (c + 2 < 64)      asm volatile("s_waitcnt vmcnt(12)" ::: "memory");
    else if (c + 1 < 64) asm volatile("s_waitcnt vmcnt(6)"  ::: "memory");
    else                 asm volatile("s_waitcnt vmcnt(0)"  ::: "memory");
    __builtin_amdgcn_s_barrier();            // all waves' chunk-c loads landed
    __builtin_amdgcn_sched_barrier(0);

    const char* cur = lds + zc * ZONE;
    short8v b0[2], b1[2], b2[2];
#pragma unroll
    for (int ng = 0; ng < 2; ++ng) {
      b0[ng] = *(const short8v*)(cur + boff + 0 * 8192 + ng * 256);
      b1[ng] = *(const short8v*)(cur + boff + 1 * 8192 + ng * 256);
      b2[ng] = *(const short8v*)(cur + boff + 2 * 8192 + ng * 256);
    }
#pragma unroll
    for (int mg = 0; mg < 4; ++mg) {
      const short8v a0 = *(const short8v*)(cur + 0 * 8192 + aoff + mg * 256);
      const short8v a1 = *(const short8v*)(cur + 1 * 8192 + aoff + mg * 256);
      const short8v a2 = *(const short8v*)(cur + 2 * 8192 + aoff + mg * 256);
#pragma unroll
      for (int ng = 0; ng < 2; ++ng) {
        float4v t = acc[mg][ng];
        t = __builtin_amdgcn_mfma_f32_16x16x32_bf16(a0, b0[ng], t, 0, 0, 0); // h1*h1
        t = __builtin_amdgcn_mfma_f32_16x16x32_bf16(a0, b1[ng], t, 0, 0, 0); // h1*h2
        t = __builtin_amdgcn_mfma_f32_16x16x32_bf16(a1, b0[ng], t, 0, 0, 0); // h2*h1
        t = __builtin_amdgcn_mfma_f32_16x16x32_bf16(a1, b1[ng], t, 0, 0, 0); // h2*h2
        t = __builtin_amdgcn_mfma_f32_16x16x32_bf16(a0, b2[ng], t, 0, 0, 0); // h1*h3
        t = __builtin_amdgcn_mfma_f32_16x16x32_bf16(a2, b0[ng], t, 0, 0, 0); // h3*h1
        acc[mg][ng] = t;
      }
    }
    __builtin_amdgcn_sched_barrier(0);
    __builtin_amdgcn_s_barrier();            // zone zc free for reuse
    zc = (zc == 2) ? 0 : zc + 1;
    zs = (zs == 2) ? 0 : zs + 1;
  }

  // C/D layout (m89-verified): col = lane&15, row = (lane>>4)*4 + reg.
  const int row0 = m0 + rsel + g16 * 4;
  const int col0 = n0 + csel + l15;
#pragma unroll
  for (int mg = 0; mg < 4; ++mg)
#pragma unroll
    for (int ng = 0; ng < 2; ++ng)
#pragma unroll
      for (int r = 0; r < 4; ++r) {
        const size_t o = (size_t)(row0 + mg * 16 + r) * DD + col0 + ng * 16;
        float v = acc[mg][ng][r];
        if (ADD) v += Cadd[o];
        Cout[o] = v;
      }
}

// ------------------------------------ XCD-sliced sparse apply (1 wave/block)
template<int HASBASE>
__global__ __launch_bounds__(64)
void spapply_sl(const float* __restrict__ M, const float* __restrict__ baseB,
                float* __restrict__ outF, const unsigned* __restrict__ sidx,
                const float* __restrict__ sval, const int* __restrict__ scnt) {
  const int b = blockIdx.y, lane = threadIdx.x;
  const int col = blockIdx.x * 256 + lane * 4;
  const int nc = scnt[b];
  const unsigned* ip = sidx + b * 64;
  const float* vp = sval + b * 64;
  const size_t ro = (size_t)b * DD + col;
  float4 a;
  if (HASBASE) a = *(const float4*)&baseB[ro];
  else         a = make_float4(0.f, 0.f, 0.f, 0.f);
  for (int t = 0; t < nc; ++t) {
    const unsigned j = ip[t];
    const float v = vp[t];
    float4 m = *(const float4*)&M[(size_t)j * DD + col];
    a.x = fmaf(v, m.x, a.x); a.y = fmaf(v, m.y, a.y);
    a.z = fmaf(v, m.z, a.z); a.w = fmaf(v, m.w, a.w);
  }
  *(float4*)&outF[ro] = a;
}

// ------------------------------------------------------------ top-k (1 wave)
__global__ __launch_bounds__(64)
void topk_kernel(const float* __restrict__ src, unsigned* __restrict__ sidx,
                 float* __restrict__ sval, int* __restrict__ scnt,
                 float* __restrict__ dense, float* __restrict__ mD,
                 int finalMode) {
  const int b = blockIdx.x;
  const int lane = threadIdx.x;
  const float* row = src + (size_t)b * DD;
  float v[32]; unsigned ab[32];
#pragma unroll
  for (int e4 = 0; e4 < 8; ++e4) {
    float4 t = *(const float4*)&row[e4*256 + lane*4];
    v[e4*4+0]=t.x; v[e4*4+1]=t.y; v[e4*4+2]=t.z; v[e4*4+3]=t.w;
  }
#pragma unroll
  for (int e = 0; e < 32; ++e) ab[e] = __float_as_uint(v[e]) & 0x7fffffffu;

  unsigned mxb = 0;
#pragma unroll
  for (int e = 0; e < 32; ++e) mxb = ab[e] > mxb ? ab[e] : mxb;
  for (int off = 32; off; off >>= 1) {
    unsigned o = (unsigned)__shfl_down((int)mxb, off);
    mxb = o > mxb ? o : mxb;
  }
  mxb = (unsigned)__shfl((int)mxb, 0);
  const int emax = (int)(mxb >> 23);

  int eStar = 0, cntAbove = 0;
  {
    int prevc = 0;
    for (int e = emax; e >= 0; --e) {
      unsigned T = ((unsigned)e) << 23;
      int c = 0;
#pragma unroll
      for (int k = 0; k < 32; ++k) c += (ab[k] >= T) ? 1 : 0;
      for (int off = 32; off; off >>= 1) c += __shfl_down(c, off);
      c = __shfl(c, 0);
      if (c >= 50) { eStar = e; cntAbove = prevc; break; }
      prevc = c;
    }
  }
  unsigned kth = ((unsigned)eStar) << 23;
  int kneed = 50 - cntAbove;

  __shared__ int hist[256];
  __shared__ int sh_sel, sh_kneed;
  for (int p = 0; p < 3; ++p) {
    const unsigned mask = (p==0) ? 0x7F800000u : (p==1) ? 0x7FFF8000u : 0x7FFFFF80u;
    const int sh = (p==0) ? 15 : (p==1) ? 7 : 0;
    for (int t = lane; t < 256; t += 64) hist[t] = 0;
    __syncthreads();
#pragma unroll
    for (int e = 0; e < 32; ++e)
      if ((ab[e] & mask) == kth) atomicAdd(&hist[(ab[e] >> sh) & 0xFF], 1);
    __syncthreads();
    int h0 = hist[lane*4+0], h1 = hist[lane*4+1], h2 = hist[lane*4+2], h3 = hist[lane*4+3];
    int s = h0 + h1 + h2 + h3;
    int x = s;
    for (int off = 1; off < 64; off <<= 1) {
      int y = __shfl_down(x, off);
      if (lane + off < 64) x += y;
    }
    int excl = x - s;
    int c3 = excl + h3, c2 = c3 + h2, c1 = c2 + h1, c0 = c1 + h0;
    if (c0 >= kneed && c1   < kneed) { sh_sel = lane*4+0; sh_kneed = kneed - c1;  }
    if (c1 >= kneed && c2   < kneed) { sh_sel = lane*4+1; sh_kneed = kneed - c2;  }
    if (c2 >= kneed && c3   < kneed) { sh_sel = lane*4+2; sh_kneed = kneed - c3;  }
    if (c3 >= kneed && excl < kneed) { sh_sel = lane*4+3; sh_kneed = kneed - excl;}
    __syncthreads();
    kth |= ((unsigned)sh_sel) << sh;
    kneed = sh_kneed;
    __syncthreads();
  }

  int base = 0;
#pragma unroll
  for (int e4 = 0; e4 < 8; ++e4) {
    float o[4];
#pragma unroll
    for (int qq = 0; qq < 4; ++qq) {
      const int e = e4*4 + qq;
      const bool sel = ab[e] >= kth;
      unsigned long long msk = __ballot(sel);
      int pre = __popcll(msk & ((1ull << lane) - 1ull));
      const unsigned gi = (unsigned)(e4*256 + lane*4 + qq);
      if (sel) {
        int slot = base + pre;
        if (slot < 64) { sidx[b*64+slot] = gi; sval[b*64+slot] = v[e]; }
        if (finalMode) atomicAdd(&mD[gi & 1023u], v[e]*v[e]);
      }
      base += __popcll(msk);
      o[qq] = sel ? v[e] : 0.f;
    }
    if (finalMode) {
      float4 t = {o[0],o[1],o[2],o[3]};
      *(float4*)&dense[(size_t)b*DD + e4*256 + lane*4] = t;
    }
  }
  if (lane == 0) scnt[b] = base < 64 ? base : 64;
}

// ------------------------------------------------------------- attention bits
__global__ __launch_bounds__(256)
void attdot_kernel(const float* __restrict__ prev, const float* __restrict__ U,
                   float* __restrict__ att) {
  const int b = blockIdx.x, p = blockIdx.y, tid = threadIdx.x;
  const float* pr = prev + ((size_t)p*NB + b) * DD;
  const float* u  = U + (size_t)b * DD;
  float s = 0.f;
#pragma unroll
  for (int h = 0; h < 2; ++h) {
    int i = (tid + h*256) * 4;
    float4 a = *(const float4*)&pr[i];
    float4 c = *(const float4*)&u[i];
    s += a.x*c.x + a.y*c.y + a.z*c.z + a.w*c.w;
  }
  for (int off = 32; off; off >>= 1) s += __shfl_down(s, off);
  __shared__ float ps[4];
  if ((tid & 63) == 0) ps[tid >> 6] = s;
  __syncthreads();
  if (tid == 0) att[(size_t)p*NB + b] = ps[0]+ps[1]+ps[2]+ps[3];
}

__global__ __launch_bounds__(256)
void softmax_kernel(const float* __restrict__ att, float* __restrict__ attw) {
  const int p = blockIdx.x, tid = threadIdx.x;
  const float* a = att + (size_t)p*NB;
  float loc[8]; float mx = -3.4e38f;
#pragma unroll
  for (int h = 0; h < 8; ++h) { loc[h] = a[tid + h*256]; mx = fmaxf(mx, loc[h]); }
  for (int off = 32; off; off >>= 1) mx = fmaxf(mx, __shfl_down(mx, off));
  __shared__ float ps[4]; __shared__ float sh_m, sh_s;
  if ((tid & 63) == 0) ps[tid >> 6] = mx;
  __syncthreads();
  if (tid == 0) sh_m = fmaxf(fmaxf(ps[0],ps[1]), fmaxf(ps[2],ps[3]));
  __syncthreads();
  const float m = sh_m;
  float sum = 0.f;
#pragma unroll
  for (int h = 0; h < 8; ++h) sum += expf(loc[h] - m);
  for (int off = 32; off; off >>= 1) sum += __shfl_down(sum, off);
  __syncthreads();
  if ((tid & 63) == 0) ps[tid >> 6] = sum;
  __syncthreads();
  if (tid == 0) sh_s = ps[0]+ps[1]+ps[2]+ps[3];
  __syncthreads();
  const float inv = 1.0f / sh_s;
#pragma unroll
  for (int h = 0; h < 8; ++h) attw[(size_t)p*NB + tid + h*256] = expf(loc[h] - m) * inv;
}

__global__ __launch_bounds__(256)
void zatt_kernel(const float* __restrict__ prev, const float* __restrict__ attw,
                 const float* __restrict__ lam, float* __restrict__ Z) {
  const int b = blockIdx.x, tid = threadIdx.x;
  __shared__ float w[8];
  if (tid < 8) w[tid] = attw[(size_t)tid*NB + b];
  __syncthreads();
  const float l2 = lam[0];
#pragma unroll
  for (int h = 0; h < 2; ++h) {
    int i = (tid + h*256) * 4;
    float4 acc = {0.f,0.f,0.f,0.f};
#pragma unroll
    for (int p = 0; p < 8; ++p) {
      float4 pv = *(const float4*)&prev[((size_t)p*NB + b)*DD + i];
      float wp = w[p];
      acc.x += wp * fminf(fmaxf(pv.x, -150.f), 150.f);
      acc.y += wp * fminf(fmaxf(pv.y, -150.f), 150.f);
      acc.z += wp * fminf(fmaxf(pv.z, -150.f), 150.f);
      acc.w += wp * fminf(fmaxf(pv.w, -150.f), 150.f);
    }
    acc.x *= l2; acc.y *= l2; acc.z *= l2; acc.w *= l2;
    *(float4*)&Z[(size_t)b*DD + i] = acc;
  }
}

__global__ __launch_bounds__(256)
void norm_kernel(float* __restrict__ mD) {
  const int tid = threadIdx.x;
  float v[4]; float mn = 3.4e38f, mx = -3.4e38f;
#pragma unroll
  for (int h = 0; h < 4; ++h) {
    v[h] = mD[tid + h*256];
    mn = fminf(mn, v[h]); mx = fmaxf(mx, v[h]);
  }
  for (int off = 32; off; off >>= 1) {
    mn = fminf(mn, __shfl_down(mn, off));
    mx = fmaxf(mx, __shfl_down(mx, off));
  }
  __shared__ float pmn[4], pmx[4]; __shared__ float smn, smx;
  if ((tid & 63) == 0) { pmn[tid>>6] = mn; pmx[tid>>6] = mx; }
  __syncthreads();
  if (tid == 0) {
    smn = fminf(fminf(pmn[0],pmn[1]), fminf(pmn[2],pmn[3]));
    smx = fmaxf(fmaxf(pmx[0],pmx[1]), fmaxf(pmx[2],pmx[3]));
  }
  __syncthreads();
  const float d = smx - smn + 1e-8f;
#pragma unroll
  for (int h = 0; h < 4; ++h) mD[tid + h*256] = (v[h] - smn) / d;
}

// ----------------------------------------------------------------- launcher
extern "C" void kernel_launch(void* const* d_in, const int* in_sizes, int n_in,
                              void* d_out, int out_size, void* d_ws, size_t ws_size,
                              hipStream_t stream) {
  const float* x    = (const float*)d_in[0];   // (2048, 2048)
  const float* prev = (const float*)d_in[1];   // (8, 2048, 2048)
  const float* Wd   = (const float*)d_in[2];   // (2048, 2048)
  const float* S    = (const float*)d_in[3];   // (2048, 2048) symmetric
  const float* lam  = (const float*)d_in[4];   // scalar

  float* out   = (float*)d_out;
  float* mD    = out;                 // 1024
  float* zlast = out + 1024;          // dense z_last; doubles as U scratch early

  float* B  = (float*)d_ws;                       // 16 MB
  float* C  = B  + (1u << 22);                    // 16 MB
  float* X1 = C  + (1u << 22);                    // 16 MB (s_t, then z_att)
  unsigned* sidx = (unsigned*)(X1 + (1u << 22));
  float*    sval = (float*)(sidx + 2048*64);
  int*      scnt = (int*)(sval + 2048*64);
  float*    att  = (float*)(scnt + 2048);
  float*    attw = att + 8*2048;
  unsigned short* PA = (unsigned short*)(attw + 8*2048);  // 3 planes, 25.2 MB
  unsigned short* PB = PA + 3 * PLANE;                    // 3 planes, 25.2 MB
  float* U = zlast;

  const dim3 gSp(8, NB);              // slice-major: linear id % 8 = slice = XCD
  const dim3 gA(16, 64);              // conv3T<128>: (m-tile, k-chunk)
  const dim3 gB(32, 64);              // conv3T<64> / tconv3: (n-tile, k-chunk)

  // split x and Wd into tiled bf16 planes; B = x @ Wd^T on the matrix cores
  conv3T<128><<<gA, 256, 0, stream>>>(x,  PA, PA + PLANE, PA + 2*PLANE);
  conv3T<64> <<<gB, 256, 0, stream>>>(Wd, PB, PB + PLANE, PB + 2*PLANE);
  gemm_bf6<0><<<256, 512, 0, stream>>>(PA, PB, nullptr, B);
  // z1 = hard_thr(B)
  topk_kernel<<<NB, 64, 0, stream>>>(B, sidx, sval, scnt, nullptr, nullptr, 0);
  // C = B + S z1   (XCD-sliced gather)
  spapply_sl<1><<<gSp, 64, 0, stream>>>(S, B, C, sidx, sval, scnt);
  // z2 = hard_thr(C)
  topk_kernel<<<NB, 64, 0, stream>>>(C, sidx, sval, scnt, nullptr, nullptr, 0);
  // s_t = Wd^T z2  (sparse rows of Wd, sliced)
  spapply_sl<0><<<gSp, 64, 0, stream>>>(Wd, nullptr, X1, sidx, sval, scnt);
  // u = s_t @ Wd : A-planes from s_t, B-planes = (Wd^T) via transposing split
  conv3T<128><<<gA, 256, 0, stream>>>(X1, PA, PA + PLANE, PA + 2*PLANE);
  tconv3<<<gB, 256, 0, stream>>>(Wd, PB, PB + PLANE, PB + 2*PLANE);
  gemm_bf6<0><<<256, 512, 0, stream>>>(PA, PB, nullptr, U);
  // att[p,b] = <prev[p,b,:], u[b,:]>
  attdot_kernel<<<dim3(NB, 8), 256, 0, stream>>>(prev, U, att);
  softmax_kernel<<<8, 256, 0, stream>>>(att, attw);
  // z_att = lambda2 * sum_p attw * clip(prev)
  zatt_kernel<<<NB, 256, 0, stream>>>(prev, attw, lam, X1);
  // iter 1 (dense z): C = B + z_att @ S  (S symmetric -> row-major == B'[n,k])
  conv3T<128><<<gA, 256, 0, stream>>>(X1, PA, PA + PLANE, PA + 2*PLANE);
  conv3T<64> <<<gB, 256, 0, stream>>>(S,  PB, PB + PLANE, PB + 2*PLANE);
  gemm_bf6<1><<<256, 512, 0, stream>>>(PA, PB, B, C);
  topk_kernel<<<NB, 64, 0, stream>>>(C, sidx, sval, scnt, nullptr, nullptr, 0);
  // it 1..9: sliced gather + threshold; final emits dense z_last + mD
  for (int it = 1; it < 10; ++it) {
    spapply_sl<1><<<gSp, 64, 0, stream>>>(S, B, C, sidx, sval, scnt);
    const int fin = (it == 9);
    if (fin) hipMemsetAsync(mD, 0, 1024 * sizeof(float), stream);
    topk_kernel<<<NB, 64, 0, stream>>>(C, sidx, sval, scnt,
                                       fin ? zlast : nullptr,
                                       fin ? mD : nullptr, fin);
  }
  // mD_norm = (mD - min) / (max - min + 1e-8)
  norm_kernel<<<1, 256, 0, stream>>>(mD);
}

// Round 4
// 1096.316 us; speedup vs baseline: 1.5213x; 1.1113x over previous
//
#include <hip/hip_runtime.h>

// DUST_65085934403760 : LIHT sparse-coding + window attention, MI355X.
// Round 11:
//  - gemm_bf6 v5: round-10 loop kept pipes ALTERNATING (wall = MFMA 1862cy +
//    LDS 1728cy per CU-chunk). Restructure to the m201 2-barrier-per-phase
//    rhythm: per chunk two phases {ds_read subtile; stage-issue; barrier;
//    lgkmcnt(0); sched_barrier; setprio(1); 24 MFMA; setprio(0); barrier},
//    with ONE counted vmcnt(6) per chunk (never 0 mid-loop). Reads target
//    data synced one chunk earlier. MFMA order per acc unchanged ->
//    bit-identical.
//  - spapply_sl v2: gather loop was latency-bound (~3x its 23us per-XCD L2
//    floor). 4 waves/block (4 b's), (sidx,sval) staged in LDS, explicit
//    4-deep load pipeline with static register rotation; fma chain stays in
//    exact ascending-t order -> bit-identical.
//  - conv/topk/attention kernels verbatim.

#define DD 2048
#define NB 2048
#define PLANE ((size_t)1 << 22)   // elements per bf16 plane (2048*2048)
#define ZONE 49152                // LDS bytes per chunk zone (A 24K + B 24K)

using short8v  = __attribute__((ext_vector_type(8))) short;
using ushort8v = __attribute__((ext_vector_type(8))) unsigned short;
using ushort4v = __attribute__((ext_vector_type(4))) unsigned short;
using float4v  = __attribute__((ext_vector_type(4))) float;

// ---------------------------------------------------------------- helpers
__device__ __forceinline__ unsigned short f2bf(float f) {
  unsigned u = __float_as_uint(f);
  u = u + 0x7fffu + ((u >> 16) & 1u);
  return (unsigned short)(u >> 16);
}
__device__ __forceinline__ float bf2f(unsigned short h) {
  return __uint_as_float((unsigned)h << 16);
}
__device__ __forceinline__ void gload16(const void* g, void* l) {
  __builtin_amdgcn_global_load_lds((const __attribute__((address_space(1))) void*)g,
                                   (__attribute__((address_space(3))) void*)l,
                                   16, 0, 0);
}

// ---------------------------------------------- fp32 -> 3 tiled bf16 planes
template<int R>
__global__ __launch_bounds__(256)
void conv3T(const float* __restrict__ in, unsigned short* __restrict__ p0,
            unsigned short* __restrict__ p1, unsigned short* __restrict__ p2) {
  __shared__ unsigned short lds3[3][4][R][8];
  const int rt = blockIdx.x, c = blockIdx.y, t = threadIdx.x;
  const int cf = (t & 7) * 4;
  const int g = cf >> 3, e0 = cf & 7;
#pragma unroll
  for (int pass = 0; pass < R / 32; ++pass) {
    const int r = pass * 32 + (t >> 3);
    float4 v = *(const float4*)(in + (size_t)(rt * R + r) * DD + c * 32 + cf);
    float vv[4] = {v.x, v.y, v.z, v.w};
    ushort4v o0, o1, o2;
#pragma unroll
    for (int j = 0; j < 4; ++j) {
      unsigned short a0 = f2bf(vv[j]); float r1 = vv[j] - bf2f(a0);
      unsigned short a1 = f2bf(r1);    float r2 = r1 - bf2f(a1);
      unsigned short a2 = f2bf(r2);
      o0[j] = a0; o1[j] = a1; o2[j] = a2;
    }
    *(ushort4v*)&lds3[0][g][r][e0] = o0;
    *(ushort4v*)&lds3[1][g][r][e0] = o1;
    *(ushort4v*)&lds3[2][g][r][e0] = o2;
  }
  __syncthreads();
  const ushort8v* src = (const ushort8v*)lds3;
  const size_t tb = ((size_t)rt * 64 + c) * (R * 32);
#pragma unroll
  for (int w = 0; w < (3 * R) / 64; ++w) {
    const int idx = w * 256 + t;
    const int p = idx / (4 * R), off = idx % (4 * R);
    unsigned short* dst = (p == 0 ? p0 : p == 1 ? p1 : p2) + tb + (size_t)off * 8;
    *(ushort8v*)dst = src[idx];
  }
}

// ------------------------- transposing split: tiled B-planes of in^T (R=64)
__global__ __launch_bounds__(256)
void tconv3(const float* __restrict__ in, unsigned short* __restrict__ p0,
            unsigned short* __restrict__ p1, unsigned short* __restrict__ p2) {
  __shared__ unsigned short lds3[3][4][64][8];
  const int nt = blockIdx.x, c = blockIdx.y, t = threadIdx.x;
  const int nf = (t & 15) * 4;
#pragma unroll
  for (int pass = 0; pass < 2; ++pass) {
    const int kr = pass * 16 + (t >> 4);
    float4 v = *(const float4*)(in + (size_t)(c * 32 + kr) * DD + nt * 64 + nf);
    float vv[4] = {v.x, v.y, v.z, v.w};
    const int g = kr >> 3, e = kr & 7;
#pragma unroll
    for (int j = 0; j < 4; ++j) {
      unsigned short a0 = f2bf(vv[j]); float r1 = vv[j] - bf2f(a0);
      unsigned short a1 = f2bf(r1);    float r2 = r1 - bf2f(a1);
      unsigned short a2 = f2bf(r2);
      lds3[0][g][nf + j][e] = a0;
      lds3[1][g][nf + j][e] = a1;
      lds3[2][g][nf + j][e] = a2;
    }
  }
  __syncthreads();
  const ushort8v* src = (const ushort8v*)lds3;
  const size_t tb = ((size_t)nt * 64 + c) * 2048;
#pragma unroll
  for (int w = 0; w < 3; ++w) {
    const int idx = w * 256 + t;
    const int p = idx >> 8, off = idx & 255;
    unsigned short* dst = (p == 0 ? p0 : p == 1 ? p1 : p2) + tb + (size_t)off * 8;
    *(ushort8v*)dst = src[idx];
  }
}

// --------------------------------------------------- bf16x6 MFMA GEMM v5
// Tile 128(m) x 128(n), K-chunk 32, 8 waves; wave = 64x32 (4mg x 2ng).
// Per chunk: 2 phases (mg{0,1} then mg{2,3}), m201 rhythm; vmcnt(6) once
// per chunk at Ph1 tail. Triple-buffered zones.
template<int ADD>
__global__ __launch_bounds__(512)
void gemm_bf6(const unsigned short* __restrict__ PA,
              const unsigned short* __restrict__ PB,
              const float* __restrict__ Cadd, float* __restrict__ Cout) {
  __shared__ char lds[3 * ZONE];
  const int tid = threadIdx.x, lane = tid & 63, wid = tid >> 6;

  // 2D XCD map: 256 blocks = 16x16 tiles; XCD covers 4m x 8n.
  const int lin = (int)blockIdx.x;
  const int xcd = lin & 7, q = lin >> 3;
  const int mt = (xcd >> 1) * 4 + (q >> 3);
  const int nt = (xcd & 1) * 8 + (q & 7);
  const int m0 = mt * 128, n0 = nt * 128;

  // stage half h of chunk c into zone base: 3 x 1KB gloads per wave.
  auto stageH = [&](char* base, int c, int h) {
    if (wid < 4) {
      const size_t at = ((size_t)mt * 64 + c) * 4096;
#pragma unroll
      for (int i = 0; i < 3; ++i) {
        const int slot = wid * 6 + h * 3 + i, p = slot >> 3, j = slot & 7;
        gload16(PA + p * PLANE + at + j * 512 + lane * 8,
                base + p * 8192 + j * 1024 + lane * 16);
      }
    } else {
#pragma unroll
      for (int i = 0; i < 3; ++i) {
        const int bb = (wid - 4) * 6 + h * 3 + i, p = bb >> 3, r = bb & 7;
        const int sub = r >> 2, j = r & 3;
        const size_t bt = ((size_t)(nt * 2 + sub) * 64 + c) * 2048;
        gload16(PB + p * PLANE + bt + j * 512 + lane * 8,
                base + 24576 + p * 8192 + sub * 4096 + j * 1024 + lane * 16);
      }
    }
  };

  float4v acc[4][2] = {};

  const int rsel = (wid >> 2) * 64;        // wave rows: 0 / 64
  const int csel = (wid & 3) * 32;         // wave cols: 0/32/64/96
  const int g16  = lane >> 4;
  const int l15  = lane & 15;
  const int aoff = g16 * 2048 + (rsel + l15) * 16;                 // + p*8192 + mg*256
  const int boff = 24576 + (csel >> 6) * 4096 + g16 * 1024
                 + ((csel & 32) + l15) * 16;                       // + p*8192 + ng*256

  // prologue: stage chunks 0 and 1; sync chunk 0.
  stageH(lds, 0, 0);        stageH(lds, 0, 1);
  stageH(lds + ZONE, 1, 0); stageH(lds + ZONE, 1, 1);
  asm volatile("s_waitcnt vmcnt(6)" ::: "memory");
  __builtin_amdgcn_s_barrier();
  __builtin_amdgcn_sched_barrier(0);

  int zc = 0, zs = 2;
  for (int c = 0; c < 64; ++c) {
    const char* cur = lds + zc * ZONE;
    char* nxt = lds + zs * ZONE;

    // ---------------- Phase 0: B frags + A frags mg0/1; MFMA mg0/1
    short8v b0[2], b1[2], b2[2];
#pragma unroll
    for (int ng = 0; ng < 2; ++ng) {
      b0[ng] = *(const short8v*)(cur + boff + 0 * 8192 + ng * 256);
      b1[ng] = *(const short8v*)(cur + boff + 1 * 8192 + ng * 256);
      b2[ng] = *(const short8v*)(cur + boff + 2 * 8192 + ng * 256);
    }
    short8v A0[2], A1[2], A2[2];
#pragma unroll
    for (int mg = 0; mg < 2; ++mg) {
      A0[mg] = *(const short8v*)(cur + 0 * 8192 + aoff + mg * 256);
      A1[mg] = *(const short8v*)(cur + 1 * 8192 + aoff + mg * 256);
      A2[mg] = *(const short8v*)(cur + 2 * 8192 + aoff + mg * 256);
    }
    if (c + 2 < 64) stageH(nxt, c + 2, 0);
    __builtin_amdgcn_s_barrier();
    asm volatile("s_waitcnt lgkmcnt(0)" ::: "memory");
    __builtin_amdgcn_sched_barrier(0);
    __builtin_amdgcn_s_setprio(1);
#pragma unroll
    for (int mg = 0; mg < 2; ++mg)
#pragma unroll
      for (int ng = 0; ng < 2; ++ng) {
        float4v t = acc[mg][ng];
        t = __builtin_amdgcn_mfma_f32_16x16x32_bf16(A0[mg], b0[ng], t, 0, 0, 0);
        t = __builtin_amdgcn_mfma_f32_16x16x32_bf16(A0[mg], b1[ng], t, 0, 0, 0);
        t = __builtin_amdgcn_mfma_f32_16x16x32_bf16(A1[mg], b0[ng], t, 0, 0, 0);
        t = __builtin_amdgcn_mfma_f32_16x16x32_bf16(A1[mg], b1[ng], t, 0, 0, 0);
        t = __builtin_amdgcn_mfma_f32_16x16x32_bf16(A0[mg], b2[ng], t, 0, 0, 0);
        t = __builtin_amdgcn_mfma_f32_16x16x32_bf16(A2[mg], b0[ng], t, 0, 0, 0);
        acc[mg][ng] = t;
      }
    __builtin_amdgcn_s_setprio(0);
    __builtin_amdgcn_sched_barrier(0);
    __builtin_amdgcn_s_barrier();

    // ---------------- Phase 1: A frags mg2/3; MFMA mg2/3; chunk-tail vmcnt
    short8v C0[2], C1[2], C2[2];
#pragma unroll
    for (int mg = 0; mg < 2; ++mg) {
      C0[mg] = *(const short8v*)(cur + 0 * 8192 + aoff + (mg + 2) * 256);
      C1[mg] = *(const short8v*)(cur + 1 * 8192 + aoff + (mg + 2) * 256);
      C2[mg] = *(const short8v*)(cur + 2 * 8192 + aoff + (mg + 2) * 256);
    }
    if (c + 2 < 64) stageH(nxt, c + 2, 1);
    // sync NEXT chunk's loads (c+1): counted, never 0 mid-loop.
    if (c + 2 < 64)      asm volatile("s_waitcnt vmcnt(6)" ::: "memory");
    else if (c + 1 < 64) asm volatile("s_waitcnt vmcnt(0)" ::: "memory");
    __builtin_amdgcn_s_barrier();
    asm volatile("s_waitcnt lgkmcnt(0)" ::: "memory");
    __builtin_amdgcn_sched_barrier(0);
    __builtin_amdgcn_s_setprio(1);
#pragma unroll
    for (int mg = 0; mg < 2; ++mg)
#pragma unroll
      for (int ng = 0; ng < 2; ++ng) {
        float4v t = acc[mg + 2][ng];
        t = __builtin_amdgcn_mfma_f32_16x16x32_bf16(C0[mg], b0[ng], t, 0, 0, 0);
        t = __builtin_amdgcn_mfma_f32_16x16x32_bf16(C0[mg], b1[ng], t, 0, 0, 0);
        t = __builtin_amdgcn_mfma_f32_16x16x32_bf16(C1[mg], b0[ng], t, 0, 0, 0);
        t = __builtin_amdgcn_mfma_f32_16x16x32_bf16(C1[mg], b1[ng], t, 0, 0, 0);
        t = __builtin_amdgcn_mfma_f32_16x16x32_bf16(C0[mg], b2[ng], t, 0, 0, 0);
        t = __builtin_amdgcn_mfma_f32_16x16x32_bf16(C2[mg], b0[ng], t, 0, 0, 0);
        acc[mg + 2][ng] = t;
      }
    __builtin_amdgcn_s_setprio(0);
    __builtin_amdgcn_sched_barrier(0);
    __builtin_amdgcn_s_barrier();

    zc = (zc == 2) ? 0 : zc + 1;
    zs = (zs == 2) ? 0 : zs + 1;
  }

  // C/D layout (m89-verified): col = lane&15, row = (lane>>4)*4 + reg.
  const int row0 = m0 + rsel + g16 * 4;
  const int col0 = n0 + csel + l15;
#pragma unroll
  for (int mg = 0; mg < 4; ++mg)
#pragma unroll
    for (int ng = 0; ng < 2; ++ng)
#pragma unroll
      for (int r = 0; r < 4; ++r) {
        const size_t o = (size_t)(row0 + mg * 16 + r) * DD + col0 + ng * 16;
        float v = acc[mg][ng][r];
        if (ADD) v += Cadd[o];
        Cout[o] = v;
      }
}

// ------------------- XCD-sliced sparse apply v2 (4 waves/block, pipelined)
// grid (8, NB/4): blockIdx.x = 256-col slice (-> XCD), wave w -> b = 4*by+w.
// out[b, cols] = (HASBASE ? base : 0) + sum_t sval[t] * M[sidx[t], cols]
// Exact ascending-t fma chain (bit-identical); loads 4-deep pipelined.
template<int HASBASE>
__global__ __launch_bounds__(256)
void spapply_sl(const float* __restrict__ M, const float* __restrict__ baseB,
                float* __restrict__ outF, const unsigned* __restrict__ sidx,
                const float* __restrict__ sval, const int* __restrict__ scnt) {
  const int lane = threadIdx.x & 63, w = threadIdx.x >> 6;
  const int b = blockIdx.y * 4 + w;
  const int col = blockIdx.x * 256 + lane * 4;
  __shared__ unsigned sj[4][64];
  __shared__ float    sv[4][64];
  sj[w][lane] = sidx[b * 64 + lane];
  sv[w][lane] = sval[b * 64 + lane];
  const int nc = scnt[b];
  __syncthreads();

  const size_t ro = (size_t)b * DD + col;
  float4 a;
  if (HASBASE) a = *(const float4*)&baseB[ro];
  else         a = make_float4(0.f, 0.f, 0.f, 0.f);

  const float* Mc = M + col;
  auto ld = [&](int t) -> float4 {
    return *(const float4*)(Mc + (size_t)sj[w][t] * DD);
  };
  auto fma4 = [&](int t, const float4& m) {
    const float v = sv[w][t];
    a.x = fmaf(v, m.x, a.x); a.y = fmaf(v, m.y, a.y);
    a.z = fmaf(v, m.z, a.z); a.w = fmaf(v, m.w, a.w);
  };

  int t = 0;
  if (nc >= 4) {
    float4 m0 = ld(0), m1 = ld(1), m2 = ld(2), m3 = ld(3);
    for (; t + 8 <= nc; t += 4) {
      float4 n0 = ld(t + 4), n1 = ld(t + 5), n2 = ld(t + 6), n3 = ld(t + 7);
      fma4(t + 0, m0); fma4(t + 1, m1); fma4(t + 2, m2); fma4(t + 3, m3);
      m0 = n0; m1 = n1; m2 = n2; m3 = n3;
    }
    fma4(t + 0, m0); fma4(t + 1, m1); fma4(t + 2, m2); fma4(t + 3, m3);
    t += 4;
  }
  for (; t < nc; ++t) {
    float4 m = ld(t);
    fma4(t, m);
  }
  *(float4*)&outF[ro] = a;
}

// ------------------------------------------------------------ top-k (1 wave)
__global__ __launch_bounds__(64)
void topk_kernel(const float* __restrict__ src, unsigned* __restrict__ sidx,
                 float* __restrict__ sval, int* __restrict__ scnt,
                 float* __restrict__ dense, float* __restrict__ mD,
                 int finalMode) {
  const int b = blockIdx.x;
  const int lane = threadIdx.x;
  const float* row = src + (size_t)b * DD;
  float v[32]; unsigned ab[32];
#pragma unroll
  for (int e4 = 0; e4 < 8; ++e4) {
    float4 t = *(const float4*)&row[e4*256 + lane*4];
    v[e4*4+0]=t.x; v[e4*4+1]=t.y; v[e4*4+2]=t.z; v[e4*4+3]=t.w;
  }
#pragma unroll
  for (int e = 0; e < 32; ++e) ab[e] = __float_as_uint(v[e]) & 0x7fffffffu;

  unsigned mxb = 0;
#pragma unroll
  for (int e = 0; e < 32; ++e) mxb = ab[e] > mxb ? ab[e] : mxb;
  for (int off = 32; off; off >>= 1) {
    unsigned o = (unsigned)__shfl_down((int)mxb, off);
    mxb = o > mxb ? o : mxb;
  }
  mxb = (unsigned)__shfl((int)mxb, 0);
  const int emax = (int)(mxb >> 23);

  int eStar = 0, cntAbove = 0;
  {
    int prevc = 0;
    for (int e = emax; e >= 0; --e) {
      unsigned T = ((unsigned)e) << 23;
      int c = 0;
#pragma unroll
      for (int k = 0; k < 32; ++k) c += (ab[k] >= T) ? 1 : 0;
      for (int off = 32; off; off >>= 1) c += __shfl_down(c, off);
      c = __shfl(c, 0);
      if (c >= 50) { eStar = e; cntAbove = prevc; break; }
      prevc = c;
    }
  }
  unsigned kth = ((unsigned)eStar) << 23;
  int kneed = 50 - cntAbove;

  __shared__ int hist[256];
  __shared__ int sh_sel, sh_kneed;
  for (int p = 0; p < 3; ++p) {
    const unsigned mask = (p==0) ? 0x7F800000u : (p==1) ? 0x7FFF8000u : 0x7FFFFF80u;
    const int sh = (p==0) ? 15 : (p==1) ? 7 : 0;
    for (int t = lane; t < 256; t += 64) hist[t] = 0;
    __syncthreads();
#pragma unroll
    for (int e = 0; e < 32; ++e)
      if ((ab[e] & mask) == kth) atomicAdd(&hist[(ab[e] >> sh) & 0xFF], 1);
    __syncthreads();
    int h0 = hist[lane*4+0], h1 = hist[lane*4+1], h2 = hist[lane*4+2], h3 = hist[lane*4+3];
    int s = h0 + h1 + h2 + h3;
    int x = s;
    for (int off = 1; off < 64; off <<= 1) {
      int y = __shfl_down(x, off);
      if (lane + off < 64) x += y;
    }
    int excl = x - s;
    int c3 = excl + h3, c2 = c3 + h2, c1 = c2 + h1, c0 = c1 + h0;
    if (c0 >= kneed && c1   < kneed) { sh_sel = lane*4+0; sh_kneed = kneed - c1;  }
    if (c1 >= kneed && c2   < kneed) { sh_sel = lane*4+1; sh_kneed = kneed - c2;  }
    if (c2 >= kneed && c3   < kneed) { sh_sel = lane*4+2; sh_kneed = kneed - c3;  }
    if (c3 >= kneed && excl < kneed) { sh_sel = lane*4+3; sh_kneed = kneed - excl;}
    __syncthreads();
    kth |= ((unsigned)sh_sel) << sh;
    kneed = sh_kneed;
    __syncthreads();
  }

  int base = 0;
#pragma unroll
  for (int e4 = 0; e4 < 8; ++e4) {
    float o[4];
#pragma unroll
    for (int qq = 0; qq < 4; ++qq) {
      const int e = e4*4 + qq;
      const bool sel = ab[e] >= kth;
      unsigned long long msk = __ballot(sel);
      int pre = __popcll(msk & ((1ull << lane) - 1ull));
      const unsigned gi = (unsigned)(e4*256 + lane*4 + qq);
      if (sel) {
        int slot = base + pre;
        if (slot < 64) { sidx[b*64+slot] = gi; sval[b*64+slot] = v[e]; }
        if (finalMode) atomicAdd(&mD[gi & 1023u], v[e]*v[e]);
      }
      base += __popcll(msk);
      o[qq] = sel ? v[e] : 0.f;
    }
    if (finalMode) {
      float4 t = {o[0],o[1],o[2],o[3]};
      *(float4*)&dense[(size_t)b*DD + e4*256 + lane*4] = t;
    }
  }
  if (lane == 0) scnt[b] = base < 64 ? base : 64;
}

// ------------------------------------------------------------- attention bits
__global__ __launch_bounds__(256)
void attdot_kernel(const float* __restrict__ prev, const float* __restrict__ U,
                   float* __restrict__ att) {
  const int b = blockIdx.x, p = blockIdx.y, tid = threadIdx.x;
  const float* pr = prev + ((size_t)p*NB + b) * DD;
  const float* u  = U + (size_t)b * DD;
  float s = 0.f;
#pragma unroll
  for (int h = 0; h < 2; ++h) {
    int i = (tid + h*256) * 4;
    float4 a = *(const float4*)&pr[i];
    float4 c = *(const float4*)&u[i];
    s += a.x*c.x + a.y*c.y + a.z*c.z + a.w*c.w;
  }
  for (int off = 32; off; off >>= 1) s += __shfl_down(s, off);
  __shared__ float ps[4];
  if ((tid & 63) == 0) ps[tid >> 6] = s;
  __syncthreads();
  if (tid == 0) att[(size_t)p*NB + b] = ps[0]+ps[1]+ps[2]+ps[3];
}

__global__ __launch_bounds__(256)
void softmax_kernel(const float* __restrict__ att, float* __restrict__ attw) {
  const int p = blockIdx.x, tid = threadIdx.x;
  const float* a = att + (size_t)p*NB;
  float loc[8]; float mx = -3.4e38f;
#pragma unroll
  for (int h = 0; h < 8; ++h) { loc[h] = a[tid + h*256]; mx = fmaxf(mx, loc[h]); }
  for (int off = 32; off; off >>= 1) mx = fmaxf(mx, __shfl_down(mx, off));
  __shared__ float ps[4]; __shared__ float sh_m, sh_s;
  if ((tid & 63) == 0) ps[tid >> 6] = mx;
  __syncthreads();
  if (tid == 0) sh_m = fmaxf(fmaxf(ps[0],ps[1]), fmaxf(ps[2],ps[3]));
  __syncthreads();
  const float m = sh_m;
  float sum = 0.f;
#pragma unroll
  for (int h = 0; h < 8; ++h) sum += expf(loc[h] - m);
  for (int off = 32; off; off >>= 1) sum += __shfl_down(sum, off);
  __syncthreads();
  if ((tid & 63) == 0) ps[tid >> 6] = sum;
  __syncthreads();
  if (tid == 0) sh_s = ps[0]+ps[1]+ps[2]+ps[3];
  __syncthreads();
  const float inv = 1.0f / sh_s;
#pragma unroll
  for (int h = 0; h < 8; ++h) attw[(size_t)p*NB + tid + h*256] = expf(loc[h] - m) * inv;
}

__global__ __launch_bounds__(256)
void zatt_kernel(const float* __restrict__ prev, const float* __restrict__ attw,
                 const float* __restrict__ lam, float* __restrict__ Z) {
  const int b = blockIdx.x, tid = threadIdx.x;
  __shared__ float w[8];
  if (tid < 8) w[tid] = attw[(size_t)tid*NB + b];
  __syncthreads();
  const float l2 = lam[0];
#pragma unroll
  for (int h = 0; h < 2; ++h) {
    int i = (tid + h*256) * 4;
    float4 acc = {0.f,0.f,0.f,0.f};
#pragma unroll
    for (int p = 0; p < 8; ++p) {
      float4 pv = *(const float4*)&prev[((size_t)p*NB + b)*DD + i];
      float wp = w[p];
      acc.x += wp * fminf(fmaxf(pv.x, -150.f), 150.f);
      acc.y += wp * fminf(fmaxf(pv.y, -150.f), 150.f);
      acc.z += wp * fminf(fmaxf(pv.z, -150.f), 150.f);
      acc.w += wp * fminf(fmaxf(pv.w, -150.f), 150.f);
    }
    acc.x *= l2; acc.y *= l2; acc.z *= l2; acc.w *= l2;
    *(float4*)&Z[(size_t)b*DD + i] = acc;
  }
}

__global__ __launch_bounds__(256)
void norm_kernel(float* __restrict__ mD) {
  const int tid = threadIdx.x;
  float v[4]; float mn = 3.4e38f, mx = -3.4e38f;
#pragma unroll
  for (int h = 0; h < 4; ++h) {
    v[h] = mD[tid + h*256];
    mn = fminf(mn, v[h]); mx = fmaxf(mx, v[h]);
  }
  for (int off = 32; off; off >>= 1) {
    mn = fminf(mn, __shfl_down(mn, off));
    mx = fmaxf(mx, __shfl_down(mx, off));
  }
  __shared__ float pmn[4], pmx[4]; __shared__ float smn, smx;
  if ((tid & 63) == 0) { pmn[tid>>6] = mn; pmx[tid>>6] = mx; }
  __syncthreads();
  if (tid == 0) {
    smn = fminf(fminf(pmn[0],pmn[1]), fminf(pmn[2],pmn[3]));
    smx = fmaxf(fmaxf(pmx[0],pmx[1]), fmaxf(pmx[2],pmx[3]));
  }
  __syncthreads();
  const float d = smx - smn + 1e-8f;
#pragma unroll
  for (int h = 0; h < 4; ++h) mD[tid + h*256] = (v[h] - smn) / d;
}

// ----------------------------------------------------------------- launcher
extern "C" void kernel_launch(void* const* d_in, const int* in_sizes, int n_in,
                              void* d_out, int out_size, void* d_ws, size_t ws_size,
                              hipStream_t stream) {
  const float* x    = (const float*)d_in[0];   // (2048, 2048)
  const float* prev = (const float*)d_in[1];   // (8, 2048, 2048)
  const float* Wd   = (const float*)d_in[2];   // (2048, 2048)
  const float* S    = (const float*)d_in[3];   // (2048, 2048) symmetric
  const float* lam  = (const float*)d_in[4];   // scalar

  float* out   = (float*)d_out;
  float* mD    = out;                 // 1024
  float* zlast = out + 1024;          // dense z_last; doubles as U scratch early

  float* B  = (float*)d_ws;                       // 16 MB
  float* C  = B  + (1u << 22);                    // 16 MB
  float* X1 = C  + (1u << 22);                    // 16 MB (s_t, then z_att)
  unsigned* sidx = (unsigned*)(X1 + (1u << 22));
  float*    sval = (float*)(sidx + 2048*64);
  int*      scnt = (int*)(sval + 2048*64);
  float*    att  = (float*)(scnt + 2048);
  float*    attw = att + 8*2048;
  unsigned short* PA = (unsigned short*)(attw + 8*2048);  // 3 planes, 25.2 MB
  unsigned short* PB = PA + 3 * PLANE;                    // 3 planes, 25.2 MB
  float* U = zlast;

  const dim3 gSp(8, NB / 4);          // slice-major: linear id % 8 = slice = XCD
  const dim3 gA(16, 64);              // conv3T<128>: (m-tile, k-chunk)
  const dim3 gB(32, 64);              // conv3T<64> / tconv3: (n-tile, k-chunk)

  // split x and Wd into tiled bf16 planes; B = x @ Wd^T on the matrix cores
  conv3T<128><<<gA, 256, 0, stream>>>(x,  PA, PA + PLANE, PA + 2*PLANE);
  conv3T<64> <<<gB, 256, 0, stream>>>(Wd, PB, PB + PLANE, PB + 2*PLANE);
  gemm_bf6<0><<<256, 512, 0, stream>>>(PA, PB, nullptr, B);
  // z1 = hard_thr(B)
  topk_kernel<<<NB, 64, 0, stream>>>(B, sidx, sval, scnt, nullptr, nullptr, 0);
  // C = B + S z1   (XCD-sliced gather)
  spapply_sl<1><<<gSp, 256, 0, stream>>>(S, B, C, sidx, sval, scnt);
  // z2 = hard_thr(C)
  topk_kernel<<<NB, 64, 0, stream>>>(C, sidx, sval, scnt, nullptr, nullptr, 0);
  // s_t = Wd^T z2  (sparse rows of Wd, sliced)
  spapply_sl<0><<<gSp, 256, 0, stream>>>(Wd, nullptr, X1, sidx, sval, scnt);
  // u = s_t @ Wd : A-planes from s_t, B-planes = (Wd^T) via transposing split
  conv3T<128><<<gA, 256, 0, stream>>>(X1, PA, PA + PLANE, PA + 2*PLANE);
  tconv3<<<gB, 256, 0, stream>>>(Wd, PB, PB + PLANE, PB + 2*PLANE);
  gemm_bf6<0><<<256, 512, 0, stream>>>(PA, PB, nullptr, U);
  // att[p,b] = <prev[p,b,:], u[b,:]>
  attdot_kernel<<<dim3(NB, 8), 256, 0, stream>>>(prev, U, att);
  softmax_kernel<<<8, 256, 0, stream>>>(att, attw);
  // z_att = lambda2 * sum_p attw * clip(prev)
  zatt_kernel<<<NB, 256, 0, stream>>>(prev, attw, lam, X1);
  // iter 1 (dense z): C = B + z_att @ S  (S symmetric -> row-major == B'[n,k])
  conv3T<128><<<gA, 256, 0, stream>>>(X1, PA, PA + PLANE, PA + 2*PLANE);
  conv3T<64> <<<gB, 256, 0, stream>>>(S,  PB, PB + PLANE, PB + 2*PLANE);
  gemm_bf6<1><<<256, 512, 0, stream>>>(PA, PB, B, C);
  topk_kernel<<<NB, 64, 0, stream>>>(C, sidx, sval, scnt, nullptr, nullptr, 0);
  // it 1..9: sliced gather + threshold; final emits dense z_last + mD
  for (int it = 1; it < 10; ++it) {
    spapply_sl<1><<<gSp, 256, 0, stream>>>(S, B, C, sidx, sval, scnt);
    const int fin = (it == 9);
    if (fin) hipMemsetAsync(mD, 0, 1024 * sizeof(float), stream);
    topk_kernel<<<NB, 64, 0, stream>>>(C, sidx, sval, scnt,
                                       fin ? zlast : nullptr,
                                       fin ? mD : nullptr, fin);
  }
  // mD_norm = (mD - min) / (max - min + 1e-8)
  norm_kernel<<<1, 256, 0, stream>>>(mD);
}